// Round 6
// baseline (2491.725 us; speedup 1.0000x reference)
//
#include <hip/hip_runtime.h>

#define NF_ATOM 9
#define NF_BOND 3
#define DD 128
#define HH 256
#define NLAYER 5

typedef float fv4 __attribute__((ext_vector_type(4)));
typedef __bf16 bfv8 __attribute__((ext_vector_type(8)));
typedef unsigned int uv4 __attribute__((ext_vector_type(4)));

__device__ inline unsigned short f2bf(float f) {
    unsigned int u = __builtin_bit_cast(unsigned int, f);
    u = u + 0x7FFFu + ((u >> 16) & 1u);
    return (unsigned short)(u >> 16);
}
__device__ inline float bf2f(unsigned short s) {
    unsigned int u = ((unsigned int)s) << 16;
    return __builtin_bit_cast(float, u);
}

// ---------- atom encoder: h0 -> bf16 state ----------
__global__ __launch_bounds__(256) void k_atom(const int* __restrict__ x,
        const float* __restrict__ emb, unsigned short* __restrict__ h, int N) {
    int gid = blockIdx.x * 256 + threadIdx.x;
    int n = gid >> 5;
    if (n >= N) return;
    int c = (gid & 31) << 2;
    const int* xr = x + n * NF_ATOM;
    float4 acc = make_float4(0.f, 0.f, 0.f, 0.f);
#pragma unroll
    for (int f = 0; f < NF_ATOM; ++f) {
        int idx = xr[f];
        float4 v = *(const float4*)(emb + ((size_t)(f * 120 + idx) * DD) + c);
        acc.x += v.x; acc.y += v.y; acc.z += v.z; acc.w += v.w;
    }
    ushort4 o;
    o.x = f2bf(acc.x); o.y = f2bf(acc.y); o.z = f2bf(acc.z); o.w = f2bf(acc.w);
    *(ushort4*)(h + (size_t)n * DD + c) = o;
}

// ---------- weight convert: f32 [K][N] -> bf16 chunk-major [l][kc][n][32k] ----------
__global__ __launch_bounds__(256) void k_wconv(const float* __restrict__ W1,
        const float* __restrict__ W2, unsigned short* __restrict__ W1t,
        unsigned short* __restrict__ W2t) {
    int id = blockIdx.x * 256 + threadIdx.x;
    const int T1 = NLAYER * 4 * 256 * 32;      // 163840
    if (id < T1) {
        int k = id & 31, n = (id >> 5) & 255, kc = (id >> 13) & 3, l = id >> 15;
        W1t[id] = f2bf(W1[((size_t)(l * 128 + kc * 32 + k)) * 256 + n]);
    } else {
        int id2 = id - T1;
        if (id2 >= NLAYER * 8 * 128 * 32) return;
        int k = id2 & 31, n = (id2 >> 5) & 127, kc = (id2 >> 12) & 7, l = id2 >> 15;
        W2t[id2] = f2bf(W2[((size_t)(l * 256 + kc * 32 + k)) * 128 + n]);
    }
}

// ---------- CSR build ----------
__global__ __launch_bounds__(256) void k_deg(const int* __restrict__ ei, int* __restrict__ deg, int E) {
    int e = blockIdx.x * 256 + threadIdx.x;
    if (e < E) atomicAdd(&deg[ei[E + e]], 1);
}
__global__ __launch_bounds__(256) void k_bsum(const int* __restrict__ deg, int* __restrict__ bsum, int N) {
    __shared__ int red[256];
    int t = threadIdx.x, b = blockIdx.x;
    int i0 = b * 1024 + t * 4;
    int s = 0;
#pragma unroll
    for (int j = 0; j < 4; ++j) if (i0 + j < N) s += deg[i0 + j];
    red[t] = s; __syncthreads();
    for (int off = 128; off > 0; off >>= 1) {
        if (t < off) red[t] += red[t + off];
        __syncthreads();
    }
    if (t == 0) bsum[b] = red[0];
}
__global__ __launch_bounds__(256) void k_bscan(const int* __restrict__ bsum, int* __restrict__ boff, int nb) {
    __shared__ int ts[256];
    int t = threadIdx.x;
    int v = (t < nb) ? bsum[t] : 0;
    ts[t] = v; __syncthreads();
    for (int off = 1; off < 256; off <<= 1) {
        int u = (t >= off) ? ts[t - off] : 0;
        __syncthreads();
        ts[t] += u;
        __syncthreads();
    }
    if (t < nb) boff[t] = ts[t] - v;   // exclusive
}
__global__ __launch_bounds__(256) void k_csr(const int* deg, const int* __restrict__ boff,
        int* rs, int N, int E) {
    __shared__ int ts[256];
    int t = threadIdx.x, b = blockIdx.x;
    int i0 = b * 1024 + t * 4;
    int d[4];
#pragma unroll
    for (int j = 0; j < 4; ++j) d[j] = (i0 + j < N) ? deg[i0 + j] : 0;
    int tsum = d[0] + d[1] + d[2] + d[3];
    ts[t] = tsum; __syncthreads();
    for (int off = 1; off < 256; off <<= 1) {
        int u = (t >= off) ? ts[t - off] : 0;
        __syncthreads();
        ts[t] += u;
        __syncthreads();
    }
    int base = boff[b] + ts[t] - tsum;
    int p = 0;
#pragma unroll
    for (int j = 0; j < 4; ++j) {
        int dj = d[j];
        if (i0 + j < N) rs[i0 + j] = base + p;
        p += dj;
    }
    if (b == 0 && t == 0) rs[N] = E;
}
// after scatter: rs[n] = end_n ; start_n = n ? rs[n-1] : 0
__global__ __launch_bounds__(256) void k_scatter(const int* __restrict__ ei,
        const int* __restrict__ ea, int* __restrict__ rs, int2* __restrict__ epack, int E) {
    int e = blockIdx.x * 256 + threadIdx.x;
    if (e < E) {
        int pos = atomicAdd(&rs[ei[E + e]], 1);
        int code = ea[e * 3 + 0] | (ea[e * 3 + 1] << 8) | (ea[e * 3 + 2] << 16);
        epack[pos] = make_int2(ei[e], code);
    }
}

// ---------- zbuild: z = (1+eps)*hn + sum_e relu(hn_src + bond), hn = relu(bn_prev(y2h)) ----------
__global__ __launch_bounds__(256) void k_zbuild(const unsigned short* __restrict__ y2h,
        const int* __restrict__ rs, const int2* __restrict__ epack,
        const float* __restrict__ bemb, const float* __restrict__ sumprev,
        const float* __restrict__ gprev, const float* __restrict__ bprev,
        const float* __restrict__ epsv, int l, int mode, float invN,
        unsigned short* __restrict__ z, int N) {
    int gid = blockIdx.x * 256 + threadIdx.x;
    int n = gid >> 5;
    if (n >= N) return;
    int c = (gid & 31) << 2;
    float sc4[4] = {1.f, 1.f, 1.f, 1.f}, sh4[4] = {0.f, 0.f, 0.f, 0.f};
    if (mode) {
#pragma unroll
        for (int j = 0; j < 4; ++j) {
            float mu = sumprev[c + j] * invN;
            float var = sumprev[DD + c + j] * invN - mu * mu;
            float r = rsqrtf(var + 1e-5f);
            float sc = gprev[c + j] * r;
            sc4[j] = sc; sh4[j] = bprev[c + j] - mu * sc;
        }
    }
    int p0 = (n == 0) ? 0 : rs[n - 1];
    int p1 = rs[n];
    float ag[4] = {0.f, 0.f, 0.f, 0.f};
    for (int p = p0; p < p1; ++p) {
        int2 ek = epack[p];
        int code = ek.y;
        ushort4 hv = *(const ushort4*)(y2h + (size_t)ek.x * DD + c);
        float hs[4] = {bf2f(hv.x), bf2f(hv.y), bf2f(hv.z), bf2f(hv.w)};
        if (mode) {
#pragma unroll
            for (int j = 0; j < 4; ++j) hs[j] = fmaxf(hs[j] * sc4[j] + sh4[j], 0.f);
        }
        float4 v0 = *(const float4*)(bemb + (size_t)(code & 255) * DD + c);
        float4 v1 = *(const float4*)(bemb + (size_t)(6 + ((code >> 8) & 255)) * DD + c);
        float4 v2 = *(const float4*)(bemb + (size_t)(12 + (code >> 16)) * DD + c);
        ag[0] += fmaxf(hs[0] + v0.x + v1.x + v2.x, 0.f);
        ag[1] += fmaxf(hs[1] + v0.y + v1.y + v2.y, 0.f);
        ag[2] += fmaxf(hs[2] + v0.z + v1.z + v2.z, 0.f);
        ag[3] += fmaxf(hs[3] + v0.w + v1.w + v2.w, 0.f);
    }
    float ep = 1.0f + epsv[l];
    ushort4 sv = *(const ushort4*)(y2h + (size_t)n * DD + c);
    float hz[4] = {bf2f(sv.x), bf2f(sv.y), bf2f(sv.z), bf2f(sv.w)};
    if (mode) {
#pragma unroll
        for (int j = 0; j < 4; ++j) hz[j] = fmaxf(hz[j] * sc4[j] + sh4[j], 0.f);
    }
    ushort4 o;
    o.x = f2bf(ep * hz[0] + ag[0]);
    o.y = f2bf(ep * hz[1] + ag[1]);
    o.z = f2bf(ep * hz[2] + ag[2]);
    o.w = f2bf(ep * hz[3] + ag[3]);
    *(ushort4*)(z + (size_t)n * DD + c) = o;
}

// ---------- GEMM1 (MFMA): y1 = z @ W1 + b1, BN1 stats; both operands via LDS ----------
__global__ __launch_bounds__(256) void k_gemm1(const unsigned short* __restrict__ z,
        const unsigned short* __restrict__ W1l, const float* __restrict__ bias,
        unsigned short* __restrict__ y1, float* __restrict__ stats, int N) {
    __shared__ uv4 zt[64 * 16];    // 16KB: A tile bf16 [64][128], swizzled granules
    __shared__ uv4 wt[256 * 4];    // 16KB: W1 chunk [256 n][32 k], swizzled
    int tid = threadIdx.x;
    int row0 = blockIdx.x * 64;
    int wave = tid >> 6, lane = tid & 63, lq = lane >> 4, lr = lane & 15;

#pragma unroll
    for (int i = 0; i < 4; ++i) {
        int idx = i * 256 + tid;          // 1024 granules
        int row = idx >> 4, gz = idx & 15;
        uv4 v = *(const uv4*)(z + (size_t)(row0 + row) * DD + gz * 8);
        zt[row * 16 + (gz ^ (row & 15))] = v;
    }

    fv4 acc[4][4];
#pragma unroll
    for (int m = 0; m < 4; ++m)
#pragma unroll
        for (int nb = 0; nb < 4; ++nb) acc[m][nb] = (fv4){0.f, 0.f, 0.f, 0.f};

    const uv4* wsrc = (const uv4*)W1l;
    for (int kc = 0; kc < 4; ++kc) {
        __syncthreads();
#pragma unroll
        for (int i = 0; i < 4; ++i) {
            int g = i * 256 + tid;
            int wn = g >> 2, gw = g & 3;
            wt[wn * 4 + (gw ^ ((wn >> 1) & 3))] = wsrc[(size_t)kc * 1024 + g];
        }
        __syncthreads();
        bfv8 a[4], b[4];
#pragma unroll
        for (int m = 0; m < 4; ++m) {
            int row = m * 16 + lr;
            a[m] = __builtin_bit_cast(bfv8, zt[row * 16 + ((kc * 4 + lq) ^ (row & 15))]);
        }
#pragma unroll
        for (int nb = 0; nb < 4; ++nb) {
            int col = wave * 64 + nb * 16 + lr;
            b[nb] = __builtin_bit_cast(bfv8, wt[col * 4 + (lq ^ ((col >> 1) & 3))]);
        }
#pragma unroll
        for (int m = 0; m < 4; ++m)
#pragma unroll
            for (int nb = 0; nb < 4; ++nb)
                acc[m][nb] = __builtin_amdgcn_mfma_f32_16x16x32_bf16(a[m], b[nb], acc[m][nb], 0, 0, 0);
    }

    float bv[4], s[4], q[4];
#pragma unroll
    for (int nb = 0; nb < 4; ++nb) {
        bv[nb] = bias[wave * 64 + nb * 16 + lr];
        s[nb] = 0.f; q[nb] = 0.f;
    }
#pragma unroll
    for (int m = 0; m < 4; ++m)
#pragma unroll
        for (int nb = 0; nb < 4; ++nb) {
            int col = wave * 64 + nb * 16 + lr;
#pragma unroll
            for (int r = 0; r < 4; ++r) {
                float v = acc[m][nb][r] + bv[nb];
                unsigned short ub = f2bf(v);
                float vr = bf2f(ub);
                int row = row0 + m * 16 + lq * 4 + r;
                y1[(size_t)row * HH + col] = ub;
                s[nb] += vr; q[nb] += vr * vr;
            }
        }
#pragma unroll
    for (int nb = 0; nb < 4; ++nb) {
        s[nb] += __shfl_xor(s[nb], 16); s[nb] += __shfl_xor(s[nb], 32);
        q[nb] += __shfl_xor(q[nb], 16); q[nb] += __shfl_xor(q[nb], 32);
    }
    if (lane < 16) {
#pragma unroll
        for (int nb = 0; nb < 4; ++nb) {
            int col = wave * 64 + nb * 16 + lr;
            atomicAdd(stats + col, s[nb]);
            atomicAdd(stats + HH + col, q[nb]);
        }
    }
}

// ---------- GEMM2 (MFMA): y2h = bf16(relu(bn1(y1)) @ W2 + b2), BN2 stats ----------
// BN1 scale/shift held in REGISTERS (g = tid&31 is staging-invariant) -> no LDS conflicts.
__global__ __launch_bounds__(256) void k_gemm2(const unsigned short* __restrict__ y1,
        const unsigned short* __restrict__ W2l, const float* __restrict__ bias,
        const float* __restrict__ sum1, const float* __restrict__ bn1g,
        const float* __restrict__ bn1b, float invN,
        unsigned short* __restrict__ y2h, float* __restrict__ stats2, int N) {
    __shared__ uv4 at[64 * 32];    // 32KB
    __shared__ uv4 wt[128 * 4];    // 8KB  (total 40960B -> 4 blocks/CU)
    int tid = threadIdx.x;
    int row0 = blockIdx.x * 64;
    int wave = tid >> 6, lane = tid & 63, lq = lane >> 4, lr = lane & 15;

    // per-thread BN1 scale/shift for its 8 channels
    int g0 = (tid & 31) * 8;
    float scr[8], shr[8];
#pragma unroll
    for (int j = 0; j < 8; ++j) {
        float mu = sum1[g0 + j] * invN;
        float var = sum1[256 + g0 + j] * invN - mu * mu;
        float r = rsqrtf(var + 1e-5f);
        float sc = bn1g[g0 + j] * r;
        scr[j] = sc; shr[j] = bn1b[g0 + j] - mu * sc;
    }

#pragma unroll
    for (int i = 0; i < 8; ++i) {
        int idx = i * 256 + tid;
        int row = idx >> 5, g = idx & 31;      // g == tid&31, matches g0
        uv4 raw = *((const uv4*)y1 + (size_t)(row0 + row) * 32 + g);
        uv4 p;
#pragma unroll
        for (int j = 0; j < 4; ++j) {
            float f0 = fmaxf(bf2f((unsigned short)(raw[j] & 0xFFFFu)) * scr[2 * j] + shr[2 * j], 0.f);
            float f1 = fmaxf(bf2f((unsigned short)(raw[j] >> 16)) * scr[2 * j + 1] + shr[2 * j + 1], 0.f);
            p[j] = (unsigned int)f2bf(f0) | ((unsigned int)f2bf(f1) << 16);
        }
        at[row * 32 + (g ^ (row & 15))] = p;
    }

    fv4 acc[4][2];
#pragma unroll
    for (int m = 0; m < 4; ++m) { acc[m][0] = (fv4){0.f,0.f,0.f,0.f}; acc[m][1] = (fv4){0.f,0.f,0.f,0.f}; }

    const uv4* wbase = (const uv4*)W2l;
    for (int kc = 0; kc < 8; ++kc) {
        __syncthreads();
#pragma unroll
        for (int i = 0; i < 2; ++i) {
            int g = i * 256 + tid;
            int wn = g >> 2, gw = g & 3;
            wt[wn * 4 + (gw ^ ((wn >> 1) & 3))] = wbase[(size_t)kc * 512 + g];
        }
        __syncthreads();
        bfv8 a[4], b[2];
#pragma unroll
        for (int m = 0; m < 4; ++m) {
            int row = m * 16 + lr;
            a[m] = __builtin_bit_cast(bfv8, at[row * 32 + ((kc * 4 + lq) ^ (row & 15))]);
        }
#pragma unroll
        for (int nb = 0; nb < 2; ++nb) {
            int col = wave * 32 + nb * 16 + lr;
            b[nb] = __builtin_bit_cast(bfv8, wt[col * 4 + (lq ^ ((col >> 1) & 3))]);
        }
#pragma unroll
        for (int m = 0; m < 4; ++m)
#pragma unroll
            for (int nb = 0; nb < 2; ++nb)
                acc[m][nb] = __builtin_amdgcn_mfma_f32_16x16x32_bf16(a[m], b[nb], acc[m][nb], 0, 0, 0);
    }

    float bv[2], s[2], q[2];
#pragma unroll
    for (int nb = 0; nb < 2; ++nb) {
        bv[nb] = bias[wave * 32 + nb * 16 + lr];
        s[nb] = 0.f; q[nb] = 0.f;
    }
#pragma unroll
    for (int m = 0; m < 4; ++m)
#pragma unroll
        for (int nb = 0; nb < 2; ++nb) {
            int col = wave * 32 + nb * 16 + lr;
#pragma unroll
            for (int r = 0; r < 4; ++r) {
                float v = acc[m][nb][r] + bv[nb];
                unsigned short ub = f2bf(v);
                float vr = bf2f(ub);
                int row = row0 + m * 16 + lq * 4 + r;
                y2h[(size_t)row * DD + col] = ub;
                s[nb] += vr; q[nb] += vr * vr;
            }
        }
#pragma unroll
    for (int nb = 0; nb < 2; ++nb) {
        s[nb] += __shfl_xor(s[nb], 16); s[nb] += __shfl_xor(s[nb], 32);
        q[nb] += __shfl_xor(q[nb], 16); q[nb] += __shfl_xor(q[nb], 32);
    }
    if (lane < 16) {
#pragma unroll
        for (int nb = 0; nb < 2; ++nb) {
            int col = wave * 32 + nb * 16 + lr;
            atomicAdd(stats2 + col, s[nb]);
            atomicAdd(stats2 + DD + col, q[nb]);
        }
    }
}

// ---------- final: out = relu(bn2(y2h)) -> f32 ----------
__global__ __launch_bounds__(256) void k_bnfinal(const unsigned short* __restrict__ y2h,
        const float* __restrict__ sum2, const float* __restrict__ g,
        const float* __restrict__ b, float* __restrict__ out, float invN, int N) {
    __shared__ float scS[128], shS[128];
    int tid = threadIdx.x;
    if (tid < 128) {
        float mu = sum2[tid] * invN;
        float var = sum2[128 + tid] * invN - mu * mu;
        float r = rsqrtf(var + 1e-5f);
        float sc = g[tid] * r;
        scS[tid] = sc; shS[tid] = b[tid] - mu * sc;
    }
    __syncthreads();
    size_t base = ((size_t)blockIdx.x * 256 + tid) * 4;
    if (base >= (size_t)N * DD) return;
    int c = (int)(base & (DD - 1));
    ushort4 v = *(const ushort4*)(y2h + base);
    float4 o;
    o.x = fmaxf(bf2f(v.x) * scS[c] + shS[c], 0.f);
    o.y = fmaxf(bf2f(v.y) * scS[c + 1] + shS[c + 1], 0.f);
    o.z = fmaxf(bf2f(v.z) * scS[c + 2] + shS[c + 2], 0.f);
    o.w = fmaxf(bf2f(v.w) * scS[c + 3] + shS[c + 3], 0.f);
    *(float4*)(out + base) = o;
}

extern "C" void kernel_launch(void* const* d_in, const int* in_sizes, int n_in,
                              void* d_out, int out_size, void* d_ws, size_t ws_size,
                              hipStream_t stream) {
    const int* x = (const int*)d_in[0];
    const int* ei = (const int*)d_in[1];
    const int* ea = (const int*)d_in[2];
    const float* atom_emb = (const float*)d_in[3];
    const float* bond_emb = (const float*)d_in[4];
    const float* W1 = (const float*)d_in[5];
    const float* b1 = (const float*)d_in[6];
    const float* bn1_g = (const float*)d_in[7];
    const float* bn1_b = (const float*)d_in[8];
    const float* W2 = (const float*)d_in[9];
    const float* b2 = (const float*)d_in[10];
    const float* epsv = (const float*)d_in[11];
    const float* obn_g = (const float*)d_in[12];
    const float* obn_b = (const float*)d_in[13];
    int N = in_sizes[0] / NF_ATOM;   // 200000 (divisible by 64)
    int E = in_sizes[1] / 2;

    char* wsb = (char*)d_ws;
    unsigned short* y2h = (unsigned short*)wsb;                        // N*128 bf16 (state)
    unsigned short* zb = (unsigned short*)(wsb + (size_t)N * 256);     // N*128 bf16
    unsigned short* y1b = (unsigned short*)(wsb + (size_t)N * 512);    // N*256 bf16
    int2* epack = (int2*)(wsb + (size_t)N * 1024);                     // E int2
    unsigned short* w1t = (unsigned short*)(wsb + (size_t)N * 1024 + (size_t)E * 8);
    unsigned short* w2t = w1t + 163840;
    int* rsarr = (int*)(w2t + 163840);                                 // N+1
    int* bsum = rsarr + (N + 1);                                       // 256
    int* boff = bsum + 256;                                            // 256
    float* st = (float*)(boff + 256);                                  // 5*768 f32
    float invN = 1.0f / (float)N;
    int nbk = (N + 1023) / 1024;

    k_wconv<<<1280, 256, 0, stream>>>(W1, W2, w1t, w2t);
    hipMemsetAsync(rsarr, 0, ((size_t)N + 1) * 4, stream);
    hipMemsetAsync(st, 0, NLAYER * 768 * sizeof(float), stream);
    k_deg<<<(E + 255) / 256, 256, 0, stream>>>(ei, rsarr, E);
    k_bsum<<<nbk, 256, 0, stream>>>(rsarr, bsum, N);
    k_bscan<<<1, 256, 0, stream>>>(bsum, boff, nbk);
    k_csr<<<nbk, 256, 0, stream>>>(rsarr, boff, rsarr, N, E);
    k_scatter<<<(E + 255) / 256, 256, 0, stream>>>(ei, ea, rsarr, epack, E);
    k_atom<<<(N * 32 + 255) / 256, 256, 0, stream>>>(x, atom_emb, y2h, N);

    int gb = N / 64;
    for (int l = 0; l < NLAYER; ++l) {
        float* sum1 = st + l * 768;
        float* sum2 = st + l * 768 + 512;
        const float* sumprev = (l == 0) ? st : (st + (l - 1) * 768 + 512);
        const float* gprev = (l == 0) ? obn_g : (obn_g + (l - 1) * DD);
        const float* bprev = (l == 0) ? obn_b : (obn_b + (l - 1) * DD);
        k_zbuild<<<(N * 32 + 255) / 256, 256, 0, stream>>>(y2h, rsarr, epack,
                bond_emb + (size_t)l * NF_BOND * 6 * DD, sumprev, gprev, bprev,
                epsv, l, (l == 0) ? 0 : 1, invN, zb, N);
        k_gemm1<<<gb, 256, 0, stream>>>(zb, w1t + (size_t)l * 32768,
                b1 + l * HH, y1b, sum1, N);
        k_gemm2<<<gb, 256, 0, stream>>>(y1b, w2t + (size_t)l * 32768, b2 + l * DD,
                sum1, bn1_g + l * HH, bn1_b + l * HH, invN, y2h, sum2, N);
    }
    k_bnfinal<<<(int)(((size_t)N * DD / 4 + 255) / 256), 256, 0, stream>>>(
            y2h, st + 4 * 768 + 512, obn_g + 4 * DD, obn_b + 4 * DD, (float*)d_out, invN, N);
}

// Round 7
// 929.671 us; speedup vs baseline: 2.6802x; 2.6802x over previous
//
#include <hip/hip_runtime.h>

#define NF_ATOM 9
#define NF_BOND 3
#define DD 128
#define HH 256
#define NLAYER 5
#define NSHARD 32

typedef float fv4 __attribute__((ext_vector_type(4)));
typedef __bf16 bfv8 __attribute__((ext_vector_type(8)));
typedef unsigned int uv4 __attribute__((ext_vector_type(4)));

__device__ inline unsigned short f2bf(float f) {
    unsigned int u = __builtin_bit_cast(unsigned int, f);
    u = u + 0x7FFFu + ((u >> 16) & 1u);
    return (unsigned short)(u >> 16);
}
__device__ inline float bf2f(unsigned short s) {
    unsigned int u = ((unsigned int)s) << 16;
    return __builtin_bit_cast(float, u);
}

// ---------- atom encoder: h0 -> bf16 state ----------
__global__ __launch_bounds__(256) void k_atom(const int* __restrict__ x,
        const float* __restrict__ emb, unsigned short* __restrict__ h, int N) {
    int gid = blockIdx.x * 256 + threadIdx.x;
    int n = gid >> 5;
    if (n >= N) return;
    int c = (gid & 31) << 2;
    const int* xr = x + n * NF_ATOM;
    float4 acc = make_float4(0.f, 0.f, 0.f, 0.f);
#pragma unroll
    for (int f = 0; f < NF_ATOM; ++f) {
        int idx = xr[f];
        float4 v = *(const float4*)(emb + ((size_t)(f * 120 + idx) * DD) + c);
        acc.x += v.x; acc.y += v.y; acc.z += v.z; acc.w += v.w;
    }
    ushort4 o;
    o.x = f2bf(acc.x); o.y = f2bf(acc.y); o.z = f2bf(acc.z); o.w = f2bf(acc.w);
    *(ushort4*)(h + (size_t)n * DD + c) = o;
}

// ---------- weight convert: f32 [K][N] -> bf16 chunk-major [l][kc][n][32k] ----------
__global__ __launch_bounds__(256) void k_wconv(const float* __restrict__ W1,
        const float* __restrict__ W2, unsigned short* __restrict__ W1t,
        unsigned short* __restrict__ W2t) {
    int id = blockIdx.x * 256 + threadIdx.x;
    const int T1 = NLAYER * 4 * 256 * 32;      // 163840
    if (id < T1) {
        int k = id & 31, n = (id >> 5) & 255, kc = (id >> 13) & 3, l = id >> 15;
        W1t[id] = f2bf(W1[((size_t)(l * 128 + kc * 32 + k)) * 256 + n]);
    } else {
        int id2 = id - T1;
        if (id2 >= NLAYER * 8 * 128 * 32) return;
        int k = id2 & 31, n = (id2 >> 5) & 127, kc = (id2 >> 12) & 7, l = id2 >> 15;
        W2t[id2] = f2bf(W2[((size_t)(l * 256 + kc * 32 + k)) * 128 + n]);
    }
}

// ---------- CSR build ----------
__global__ __launch_bounds__(256) void k_deg(const int* __restrict__ ei, int* __restrict__ deg, int E) {
    int e = blockIdx.x * 256 + threadIdx.x;
    if (e < E) atomicAdd(&deg[ei[E + e]], 1);
}
__global__ __launch_bounds__(256) void k_bsum(const int* __restrict__ deg, int* __restrict__ bsum, int N) {
    __shared__ int red[256];
    int t = threadIdx.x, b = blockIdx.x;
    int i0 = b * 1024 + t * 4;
    int s = 0;
#pragma unroll
    for (int j = 0; j < 4; ++j) if (i0 + j < N) s += deg[i0 + j];
    red[t] = s; __syncthreads();
    for (int off = 128; off > 0; off >>= 1) {
        if (t < off) red[t] += red[t + off];
        __syncthreads();
    }
    if (t == 0) bsum[b] = red[0];
}
__global__ __launch_bounds__(256) void k_bscan(const int* __restrict__ bsum, int* __restrict__ boff, int nb) {
    __shared__ int ts[256];
    int t = threadIdx.x;
    int v = (t < nb) ? bsum[t] : 0;
    ts[t] = v; __syncthreads();
    for (int off = 1; off < 256; off <<= 1) {
        int u = (t >= off) ? ts[t - off] : 0;
        __syncthreads();
        ts[t] += u;
        __syncthreads();
    }
    if (t < nb) boff[t] = ts[t] - v;   // exclusive
}
__global__ __launch_bounds__(256) void k_csr(const int* deg, const int* __restrict__ boff,
        int* rs, int N, int E) {
    __shared__ int ts[256];
    int t = threadIdx.x, b = blockIdx.x;
    int i0 = b * 1024 + t * 4;
    int d[4];
#pragma unroll
    for (int j = 0; j < 4; ++j) d[j] = (i0 + j < N) ? deg[i0 + j] : 0;
    int tsum = d[0] + d[1] + d[2] + d[3];
    ts[t] = tsum; __syncthreads();
    for (int off = 1; off < 256; off <<= 1) {
        int u = (t >= off) ? ts[t - off] : 0;
        __syncthreads();
        ts[t] += u;
        __syncthreads();
    }
    int base = boff[b] + ts[t] - tsum;
    int p = 0;
#pragma unroll
    for (int j = 0; j < 4; ++j) {
        int dj = d[j];
        if (i0 + j < N) rs[i0 + j] = base + p;
        p += dj;
    }
    if (b == 0 && t == 0) rs[N] = E;
}
// after scatter: rs[n] = end_n ; start_n = n ? rs[n-1] : 0
__global__ __launch_bounds__(256) void k_scatter(const int* __restrict__ ei,
        const int* __restrict__ ea, int* __restrict__ rs, int2* __restrict__ epack, int E) {
    int e = blockIdx.x * 256 + threadIdx.x;
    if (e < E) {
        int pos = atomicAdd(&rs[ei[E + e]], 1);
        int code = ea[e * 3 + 0] | (ea[e * 3 + 1] << 8) | (ea[e * 3 + 2] << 16);
        epack[pos] = make_int2(ei[e], code);
    }
}

// ---------- shard reduce: out[t] = sum_s shard[s*C + t] ----------
__global__ __launch_bounds__(256) void k_red(const float* __restrict__ sh,
        float* __restrict__ out, int C) {
    int t = blockIdx.x * 256 + threadIdx.x;
    if (t >= C) return;
    float a = 0.f;
#pragma unroll
    for (int s = 0; s < NSHARD; ++s) a += sh[s * C + t];
    out[t] = a;
}

// ---------- zbuild: z = (1+eps)*hn + sum_e relu(hn_src + bond), hn = relu(bn_prev(y2h)) ----------
__global__ __launch_bounds__(256) void k_zbuild(const unsigned short* __restrict__ y2h,
        const int* __restrict__ rs, const int2* __restrict__ epack,
        const float* __restrict__ bemb, const float* __restrict__ sumprev,
        const float* __restrict__ gprev, const float* __restrict__ bprev,
        const float* __restrict__ epsv, int l, int mode, float invN,
        unsigned short* __restrict__ z, int N) {
    int gid = blockIdx.x * 256 + threadIdx.x;
    int n = gid >> 5;
    if (n >= N) return;
    int c = (gid & 31) << 2;
    float sc4[4] = {1.f, 1.f, 1.f, 1.f}, sh4[4] = {0.f, 0.f, 0.f, 0.f};
    if (mode) {
#pragma unroll
        for (int j = 0; j < 4; ++j) {
            float mu = sumprev[c + j] * invN;
            float var = sumprev[DD + c + j] * invN - mu * mu;
            float r = rsqrtf(var + 1e-5f);
            float sc = gprev[c + j] * r;
            sc4[j] = sc; sh4[j] = bprev[c + j] - mu * sc;
        }
    }
    int p0 = (n == 0) ? 0 : rs[n - 1];
    int p1 = rs[n];
    float ag[4] = {0.f, 0.f, 0.f, 0.f};
    for (int p = p0; p < p1; ++p) {
        int2 ek = epack[p];
        int code = ek.y;
        ushort4 hv = *(const ushort4*)(y2h + (size_t)ek.x * DD + c);
        float hs[4] = {bf2f(hv.x), bf2f(hv.y), bf2f(hv.z), bf2f(hv.w)};
        if (mode) {
#pragma unroll
            for (int j = 0; j < 4; ++j) hs[j] = fmaxf(hs[j] * sc4[j] + sh4[j], 0.f);
        }
        float4 v0 = *(const float4*)(bemb + (size_t)(code & 255) * DD + c);
        float4 v1 = *(const float4*)(bemb + (size_t)(6 + ((code >> 8) & 255)) * DD + c);
        float4 v2 = *(const float4*)(bemb + (size_t)(12 + (code >> 16)) * DD + c);
        ag[0] += fmaxf(hs[0] + v0.x + v1.x + v2.x, 0.f);
        ag[1] += fmaxf(hs[1] + v0.y + v1.y + v2.y, 0.f);
        ag[2] += fmaxf(hs[2] + v0.z + v1.z + v2.z, 0.f);
        ag[3] += fmaxf(hs[3] + v0.w + v1.w + v2.w, 0.f);
    }
    float ep = 1.0f + epsv[l];
    ushort4 sv = *(const ushort4*)(y2h + (size_t)n * DD + c);
    float hz[4] = {bf2f(sv.x), bf2f(sv.y), bf2f(sv.z), bf2f(sv.w)};
    if (mode) {
#pragma unroll
        for (int j = 0; j < 4; ++j) hz[j] = fmaxf(hz[j] * sc4[j] + sh4[j], 0.f);
    }
    ushort4 o;
    o.x = f2bf(ep * hz[0] + ag[0]);
    o.y = f2bf(ep * hz[1] + ag[1]);
    o.z = f2bf(ep * hz[2] + ag[2]);
    o.w = f2bf(ep * hz[3] + ag[3]);
    *(ushort4*)(z + (size_t)n * DD + c) = o;
}

// ---------- GEMM1 (MFMA): y1 = z @ W1 + b1, sharded BN1 stats ----------
__global__ __launch_bounds__(256) void k_gemm1(const unsigned short* __restrict__ z,
        const unsigned short* __restrict__ W1l, const float* __restrict__ bias,
        unsigned short* __restrict__ y1, float* __restrict__ shard, int N) {
    __shared__ uv4 zt[64 * 16];    // 16KB
    __shared__ uv4 wt[256 * 4];    // 16KB
    int tid = threadIdx.x;
    int row0 = blockIdx.x * 64;
    int wave = tid >> 6, lane = tid & 63, lq = lane >> 4, lr = lane & 15;
    int rbase = tid >> 4, gz = tid & 15;

    // prefetch A tile (all loads in flight before use)
    uv4 zr[4];
#pragma unroll
    for (int i = 0; i < 4; ++i)
        zr[i] = *(const uv4*)(z + (size_t)(row0 + i * 16 + rbase) * DD + gz * 8);
    // prefetch W chunk 0
    const uv4* wsrc = (const uv4*)W1l;
    uv4 wr[4];
#pragma unroll
    for (int i = 0; i < 4; ++i) wr[i] = wsrc[i * 256 + tid];
#pragma unroll
    for (int i = 0; i < 4; ++i) {
        int row = i * 16 + rbase;
        zt[row * 16 + (gz ^ (row & 15))] = zr[i];
    }

    fv4 acc[4][4];
#pragma unroll
    for (int m = 0; m < 4; ++m)
#pragma unroll
        for (int nb = 0; nb < 4; ++nb) acc[m][nb] = (fv4){0.f, 0.f, 0.f, 0.f};

    for (int kc = 0; kc < 4; ++kc) {
        __syncthreads();
#pragma unroll
        for (int i = 0; i < 4; ++i) {
            int g = i * 256 + tid;
            int wn = g >> 2, gw = g & 3;
            wt[wn * 4 + (gw ^ ((wn >> 1) & 3))] = wr[i];
        }
        __syncthreads();
        if (kc < 3) {
#pragma unroll
            for (int i = 0; i < 4; ++i) wr[i] = wsrc[(size_t)(kc + 1) * 1024 + i * 256 + tid];
        }
        bfv8 a[4], b[4];
#pragma unroll
        for (int m = 0; m < 4; ++m) {
            int row = m * 16 + lr;
            a[m] = __builtin_bit_cast(bfv8, zt[row * 16 + ((kc * 4 + lq) ^ (row & 15))]);
        }
#pragma unroll
        for (int nb = 0; nb < 4; ++nb) {
            int col = wave * 64 + nb * 16 + lr;
            b[nb] = __builtin_bit_cast(bfv8, wt[col * 4 + (lq ^ ((col >> 1) & 3))]);
        }
#pragma unroll
        for (int m = 0; m < 4; ++m)
#pragma unroll
            for (int nb = 0; nb < 4; ++nb)
                acc[m][nb] = __builtin_amdgcn_mfma_f32_16x16x32_bf16(a[m], b[nb], acc[m][nb], 0, 0, 0);
    }

    float bv[4], s[4], q[4];
#pragma unroll
    for (int nb = 0; nb < 4; ++nb) {
        bv[nb] = bias[wave * 64 + nb * 16 + lr];
        s[nb] = 0.f; q[nb] = 0.f;
    }
#pragma unroll
    for (int m = 0; m < 4; ++m)
#pragma unroll
        for (int nb = 0; nb < 4; ++nb) {
            int col = wave * 64 + nb * 16 + lr;
#pragma unroll
            for (int r = 0; r < 4; ++r) {
                float v = acc[m][nb][r] + bv[nb];
                unsigned short ub = f2bf(v);
                float vr = bf2f(ub);
                int row = row0 + m * 16 + lq * 4 + r;
                y1[(size_t)row * HH + col] = ub;
                s[nb] += vr; q[nb] += vr * vr;
            }
        }
#pragma unroll
    for (int nb = 0; nb < 4; ++nb) {
        s[nb] += __shfl_xor(s[nb], 16); s[nb] += __shfl_xor(s[nb], 32);
        q[nb] += __shfl_xor(q[nb], 16); q[nb] += __shfl_xor(q[nb], 32);
    }
    if (lane < 16) {
        int shb = (blockIdx.x & (NSHARD - 1)) * 512;
#pragma unroll
        for (int nb = 0; nb < 4; ++nb) {
            int col = wave * 64 + nb * 16 + lr;
            atomicAdd(shard + shb + col, s[nb]);
            atomicAdd(shard + shb + 256 + col, q[nb]);
        }
    }
}

// ---------- GEMM2 (MFMA): y2h = bf16(relu(bn1(y1)) @ W2 + b2), sharded BN2 stats ----------
__global__ __launch_bounds__(256) void k_gemm2(const unsigned short* __restrict__ y1,
        const unsigned short* __restrict__ W2l, const float* __restrict__ bias,
        const float* __restrict__ sum1, const float* __restrict__ bn1g,
        const float* __restrict__ bn1b, float invN,
        unsigned short* __restrict__ y2h, float* __restrict__ shard, int N) {
    __shared__ uv4 at[64 * 32];    // 32KB
    __shared__ uv4 wt[128 * 4];    // 8KB
    int tid = threadIdx.x;
    int row0 = blockIdx.x * 64;
    int wave = tid >> 6, lane = tid & 63, lq = lane >> 4, lr = lane & 15;
    int rbase = tid >> 5, g = tid & 31;

    // prefetch full A tile (8 loads in flight) ...
    uv4 raw[8];
#pragma unroll
    for (int i = 0; i < 8; ++i)
        raw[i] = *((const uv4*)y1 + (size_t)(row0 + i * 8 + rbase) * 32 + g);
    // ... and W chunk 0
    const uv4* wbase = (const uv4*)W2l;
    uv4 wr[2];
    wr[0] = wbase[tid]; wr[1] = wbase[256 + tid];

    // per-thread BN1 scale/shift for its 8 channels (computed while loads fly)
    int g0 = g * 8;
    float scr[8], shr[8];
#pragma unroll
    for (int j = 0; j < 8; ++j) {
        float mu = sum1[g0 + j] * invN;
        float var = sum1[256 + g0 + j] * invN - mu * mu;
        float r = rsqrtf(var + 1e-5f);
        float sc = bn1g[g0 + j] * r;
        scr[j] = sc; shr[j] = bn1b[g0 + j] - mu * sc;
    }

#pragma unroll
    for (int i = 0; i < 8; ++i) {
        int row = i * 8 + rbase;
        uv4 p;
#pragma unroll
        for (int j = 0; j < 4; ++j) {
            float f0 = fmaxf(bf2f((unsigned short)(raw[i][j] & 0xFFFFu)) * scr[2 * j] + shr[2 * j], 0.f);
            float f1 = fmaxf(bf2f((unsigned short)(raw[i][j] >> 16)) * scr[2 * j + 1] + shr[2 * j + 1], 0.f);
            p[j] = (unsigned int)f2bf(f0) | ((unsigned int)f2bf(f1) << 16);
        }
        at[row * 32 + (g ^ (row & 15))] = p;
    }

    fv4 acc[4][2];
#pragma unroll
    for (int m = 0; m < 4; ++m) { acc[m][0] = (fv4){0.f,0.f,0.f,0.f}; acc[m][1] = (fv4){0.f,0.f,0.f,0.f}; }

    for (int kc = 0; kc < 8; ++kc) {
        __syncthreads();
        {
            int g2 = tid, wn = g2 >> 2, gw = g2 & 3;
            wt[wn * 4 + (gw ^ ((wn >> 1) & 3))] = wr[0];
            int g3 = 256 + tid, wn3 = g3 >> 2, gw3 = g3 & 3;
            wt[wn3 * 4 + (gw3 ^ ((wn3 >> 1) & 3))] = wr[1];
        }
        __syncthreads();
        if (kc < 7) {
            wr[0] = wbase[(size_t)(kc + 1) * 512 + tid];
            wr[1] = wbase[(size_t)(kc + 1) * 512 + 256 + tid];
        }
        bfv8 a[4], b[2];
#pragma unroll
        for (int m = 0; m < 4; ++m) {
            int row = m * 16 + lr;
            a[m] = __builtin_bit_cast(bfv8, at[row * 32 + ((kc * 4 + lq) ^ (row & 15))]);
        }
#pragma unroll
        for (int nb = 0; nb < 2; ++nb) {
            int col = wave * 32 + nb * 16 + lr;
            b[nb] = __builtin_bit_cast(bfv8, wt[col * 4 + (lq ^ ((col >> 1) & 3))]);
        }
#pragma unroll
        for (int m = 0; m < 4; ++m)
#pragma unroll
            for (int nb = 0; nb < 2; ++nb)
                acc[m][nb] = __builtin_amdgcn_mfma_f32_16x16x32_bf16(a[m], b[nb], acc[m][nb], 0, 0, 0);
    }

    float bv[2], s[2], q[2];
#pragma unroll
    for (int nb = 0; nb < 2; ++nb) {
        bv[nb] = bias[wave * 32 + nb * 16 + lr];
        s[nb] = 0.f; q[nb] = 0.f;
    }
#pragma unroll
    for (int m = 0; m < 4; ++m)
#pragma unroll
        for (int nb = 0; nb < 2; ++nb) {
            int col = wave * 32 + nb * 16 + lr;
#pragma unroll
            for (int r = 0; r < 4; ++r) {
                float v = acc[m][nb][r] + bv[nb];
                unsigned short ub = f2bf(v);
                float vr = bf2f(ub);
                int row = row0 + m * 16 + lq * 4 + r;
                y2h[(size_t)row * DD + col] = ub;
                s[nb] += vr; q[nb] += vr * vr;
            }
        }
#pragma unroll
    for (int nb = 0; nb < 2; ++nb) {
        s[nb] += __shfl_xor(s[nb], 16); s[nb] += __shfl_xor(s[nb], 32);
        q[nb] += __shfl_xor(q[nb], 16); q[nb] += __shfl_xor(q[nb], 32);
    }
    if (lane < 16) {
        int shb = (blockIdx.x & (NSHARD - 1)) * 256;
#pragma unroll
        for (int nb = 0; nb < 2; ++nb) {
            int col = wave * 32 + nb * 16 + lr;
            atomicAdd(shard + shb + col, s[nb]);
            atomicAdd(shard + shb + 128 + col, q[nb]);
        }
    }
}

// ---------- final: out = relu(bn2(y2h)) -> f32 ----------
__global__ __launch_bounds__(256) void k_bnfinal(const unsigned short* __restrict__ y2h,
        const float* __restrict__ sum2, const float* __restrict__ g,
        const float* __restrict__ b, float* __restrict__ out, float invN, int N) {
    __shared__ float scS[128], shS[128];
    int tid = threadIdx.x;
    if (tid < 128) {
        float mu = sum2[tid] * invN;
        float var = sum2[128 + tid] * invN - mu * mu;
        float r = rsqrtf(var + 1e-5f);
        float sc = g[tid] * r;
        scS[tid] = sc; shS[tid] = b[tid] - mu * sc;
    }
    __syncthreads();
    size_t base = ((size_t)blockIdx.x * 256 + tid) * 4;
    if (base >= (size_t)N * DD) return;
    int c = (int)(base & (DD - 1));
    ushort4 v = *(const ushort4*)(y2h + base);
    float4 o;
    o.x = fmaxf(bf2f(v.x) * scS[c] + shS[c], 0.f);
    o.y = fmaxf(bf2f(v.y) * scS[c + 1] + shS[c + 1], 0.f);
    o.z = fmaxf(bf2f(v.z) * scS[c + 2] + shS[c + 2], 0.f);
    o.w = fmaxf(bf2f(v.w) * scS[c + 3] + shS[c + 3], 0.f);
    *(float4*)(out + base) = o;
}

extern "C" void kernel_launch(void* const* d_in, const int* in_sizes, int n_in,
                              void* d_out, int out_size, void* d_ws, size_t ws_size,
                              hipStream_t stream) {
    const int* x = (const int*)d_in[0];
    const int* ei = (const int*)d_in[1];
    const int* ea = (const int*)d_in[2];
    const float* atom_emb = (const float*)d_in[3];
    const float* bond_emb = (const float*)d_in[4];
    const float* W1 = (const float*)d_in[5];
    const float* b1 = (const float*)d_in[6];
    const float* bn1_g = (const float*)d_in[7];
    const float* bn1_b = (const float*)d_in[8];
    const float* W2 = (const float*)d_in[9];
    const float* b2 = (const float*)d_in[10];
    const float* epsv = (const float*)d_in[11];
    const float* obn_g = (const float*)d_in[12];
    const float* obn_b = (const float*)d_in[13];
    int N = in_sizes[0] / NF_ATOM;   // 200000 (divisible by 64)
    int E = in_sizes[1] / 2;

    char* wsb = (char*)d_ws;
    unsigned short* y2h = (unsigned short*)wsb;                        // N*128 bf16 (state)
    unsigned short* zb = (unsigned short*)(wsb + (size_t)N * 256);     // N*128 bf16
    unsigned short* y1b = (unsigned short*)(wsb + (size_t)N * 512);    // N*256 bf16
    int2* epack = (int2*)(wsb + (size_t)N * 1024);                     // E int2
    unsigned short* w1t = (unsigned short*)(wsb + (size_t)N * 1024 + (size_t)E * 8);
    unsigned short* w2t = w1t + 163840;
    int* rsarr = (int*)(w2t + 163840);                                 // N+1
    int* bsum = rsarr + (N + 1);                                       // 256
    int* boff = bsum + 256;                                            // 256
    float* st = (float*)(boff + 256);                                  // dense: 5*768 f32
    float* shard1 = st + NLAYER * 768;                                 // 32*512 f32
    float* shard2 = shard1 + NSHARD * 512;                             // 32*256 f32
    float invN = 1.0f / (float)N;
    int nbk = (N + 1023) / 1024;

    k_wconv<<<1280, 256, 0, stream>>>(W1, W2, w1t, w2t);
    hipMemsetAsync(rsarr, 0, ((size_t)N + 1) * 4, stream);
    k_deg<<<(E + 255) / 256, 256, 0, stream>>>(ei, rsarr, E);
    k_bsum<<<nbk, 256, 0, stream>>>(rsarr, bsum, N);
    k_bscan<<<1, 256, 0, stream>>>(bsum, boff, nbk);
    k_csr<<<nbk, 256, 0, stream>>>(rsarr, boff, rsarr, N, E);
    k_scatter<<<(E + 255) / 256, 256, 0, stream>>>(ei, ea, rsarr, epack, E);
    k_atom<<<(N * 32 + 255) / 256, 256, 0, stream>>>(x, atom_emb, y2h, N);

    int gb = N / 64;
    for (int l = 0; l < NLAYER; ++l) {
        float* sum1 = st + l * 768;
        float* sum2 = st + l * 768 + 512;
        const float* sumprev = (l == 0) ? st : (st + (l - 1) * 768 + 512);
        const float* gprev = (l == 0) ? obn_g : (obn_g + (l - 1) * DD);
        const float* bprev = (l == 0) ? obn_b : (obn_b + (l - 1) * DD);
        hipMemsetAsync(shard1, 0, (size_t)NSHARD * 768 * sizeof(float), stream);
        k_zbuild<<<(N * 32 + 255) / 256, 256, 0, stream>>>(y2h, rsarr, epack,
                bond_emb + (size_t)l * NF_BOND * 6 * DD, sumprev, gprev, bprev,
                epsv, l, (l == 0) ? 0 : 1, invN, zb, N);
        k_gemm1<<<gb, 256, 0, stream>>>(zb, w1t + (size_t)l * 32768,
                b1 + l * HH, y1b, shard1, N);
        k_red<<<2, 256, 0, stream>>>(shard1, sum1, 512);
        k_gemm2<<<gb, 256, 0, stream>>>(y1b, w2t + (size_t)l * 32768, b2 + l * DD,
                sum1, bn1_g + l * HH, bn1_b + l * HH, invN, y2h, shard2, N);
        k_red<<<1, 256, 0, stream>>>(shard2, sum2, 256);
    }
    k_bnfinal<<<(int)(((size_t)N * DD / 4 + 255) / 256), 256, 0, stream>>>(
            y2h, st + 4 * 768 + 512, obn_g + 4 * DD, obn_b + 4 * DD, (float*)d_out, invN, N);
}

// Round 8
// 852.244 us; speedup vs baseline: 2.9237x; 1.0909x over previous
//
#include <hip/hip_runtime.h>

#define NF_ATOM 9
#define NF_BOND 3
#define DD 128
#define HH 256
#define NLAYER 5
#define NSHARD 32
#define NCODE 216

typedef float fv4 __attribute__((ext_vector_type(4)));
typedef __bf16 bfv8 __attribute__((ext_vector_type(8)));
typedef unsigned int uv4 __attribute__((ext_vector_type(4)));

__device__ inline unsigned short f2bf(float f) {
    unsigned int u = __builtin_bit_cast(unsigned int, f);
    u = u + 0x7FFFu + ((u >> 16) & 1u);
    return (unsigned short)(u >> 16);
}
__device__ inline float bf2f(unsigned short s) {
    unsigned int u = ((unsigned int)s) << 16;
    return __builtin_bit_cast(float, u);
}

// ---------- atom encoder: h0 -> bf16 state ----------
__global__ __launch_bounds__(256) void k_atom(const int* __restrict__ x,
        const float* __restrict__ emb, unsigned short* __restrict__ h, int N) {
    int gid = blockIdx.x * 256 + threadIdx.x;
    int n = gid >> 5;
    if (n >= N) return;
    int c = (gid & 31) << 2;
    const int* xr = x + n * NF_ATOM;
    float4 acc = make_float4(0.f, 0.f, 0.f, 0.f);
#pragma unroll
    for (int f = 0; f < NF_ATOM; ++f) {
        int idx = xr[f];
        float4 v = *(const float4*)(emb + ((size_t)(f * 120 + idx) * DD) + c);
        acc.x += v.x; acc.y += v.y; acc.z += v.z; acc.w += v.w;
    }
    ushort4 o;
    o.x = f2bf(acc.x); o.y = f2bf(acc.y); o.z = f2bf(acc.z); o.w = f2bf(acc.w);
    *(ushort4*)(h + (size_t)n * DD + c) = o;
}

// ---------- weight convert: f32 [K][N] -> bf16 chunk-major [l][kc][n][32k] ----------
__global__ __launch_bounds__(256) void k_wconv(const float* __restrict__ W1,
        const float* __restrict__ W2, unsigned short* __restrict__ W1t,
        unsigned short* __restrict__ W2t) {
    int id = blockIdx.x * 256 + threadIdx.x;
    const int T1 = NLAYER * 4 * 256 * 32;      // 163840
    if (id < T1) {
        int k = id & 31, n = (id >> 5) & 255, kc = (id >> 13) & 3, l = id >> 15;
        W1t[id] = f2bf(W1[((size_t)(l * 128 + kc * 32 + k)) * 256 + n]);
    } else {
        int id2 = id - T1;
        if (id2 >= NLAYER * 8 * 128 * 32) return;
        int k = id2 & 31, n = (id2 >> 5) & 127, kc = (id2 >> 12) & 7, l = id2 >> 15;
        W2t[id2] = f2bf(W2[((size_t)(l * 256 + kc * 32 + k)) * 128 + n]);
    }
}

// ---------- bond-sum table: bsum[l][code][c] = emb0[a0]+emb1[a1]+emb2[a2] ----------
__global__ __launch_bounds__(256) void k_bsumtab(const float* __restrict__ bemb,
        float* __restrict__ tab) {
    int id = blockIdx.x * 256 + threadIdx.x;
    if (id >= NLAYER * NCODE * DD) return;
    int c = id & 127;
    int code = (id >> 7) % NCODE;
    int l = id / (NCODE * DD);
    int a0 = code % 6, a1 = (code / 6) % 6, a2 = code / 36;
    const float* bl = bemb + (size_t)l * NF_BOND * 6 * DD;
    tab[id] = bl[(0 * 6 + a0) * DD + c] + bl[(1 * 6 + a1) * DD + c] + bl[(2 * 6 + a2) * DD + c];
}

// ---------- CSR build ----------
__global__ __launch_bounds__(256) void k_deg(const int* __restrict__ ei, int* __restrict__ deg, int E) {
    int e = blockIdx.x * 256 + threadIdx.x;
    if (e < E) atomicAdd(&deg[ei[E + e]], 1);
}
__global__ __launch_bounds__(256) void k_bsum(const int* __restrict__ deg, int* __restrict__ bsum, int N) {
    __shared__ int red[256];
    int t = threadIdx.x, b = blockIdx.x;
    int i0 = b * 1024 + t * 4;
    int s = 0;
#pragma unroll
    for (int j = 0; j < 4; ++j) if (i0 + j < N) s += deg[i0 + j];
    red[t] = s; __syncthreads();
    for (int off = 128; off > 0; off >>= 1) {
        if (t < off) red[t] += red[t + off];
        __syncthreads();
    }
    if (t == 0) bsum[b] = red[0];
}
__global__ __launch_bounds__(256) void k_bscan(const int* __restrict__ bsum, int* __restrict__ boff, int nb) {
    __shared__ int ts[256];
    int t = threadIdx.x;
    int v = (t < nb) ? bsum[t] : 0;
    ts[t] = v; __syncthreads();
    for (int off = 1; off < 256; off <<= 1) {
        int u = (t >= off) ? ts[t - off] : 0;
        __syncthreads();
        ts[t] += u;
        __syncthreads();
    }
    if (t < nb) boff[t] = ts[t] - v;   // exclusive
}
__global__ __launch_bounds__(256) void k_csr(const int* deg, const int* __restrict__ boff,
        int* rs, int N, int E) {
    __shared__ int ts[256];
    int t = threadIdx.x, b = blockIdx.x;
    int i0 = b * 1024 + t * 4;
    int d[4];
#pragma unroll
    for (int j = 0; j < 4; ++j) d[j] = (i0 + j < N) ? deg[i0 + j] : 0;
    int tsum = d[0] + d[1] + d[2] + d[3];
    ts[t] = tsum; __syncthreads();
    for (int off = 1; off < 256; off <<= 1) {
        int u = (t >= off) ? ts[t - off] : 0;
        __syncthreads();
        ts[t] += u;
        __syncthreads();
    }
    int base = boff[b] + ts[t] - tsum;
    int p = 0;
#pragma unroll
    for (int j = 0; j < 4; ++j) {
        int dj = d[j];
        if (i0 + j < N) rs[i0 + j] = base + p;
        p += dj;
    }
    if (b == 0 && t == 0) rs[N] = E;
}
// after scatter: rs[n] = end_n ; start_n = n ? rs[n-1] : 0
// packed record: src (18 bits) | code6 << 18
__global__ __launch_bounds__(256) void k_scatter(const int* __restrict__ ei,
        const int* __restrict__ ea, int* __restrict__ rs, int* __restrict__ epack, int E) {
    int e = blockIdx.x * 256 + threadIdx.x;
    if (e < E) {
        int pos = atomicAdd(&rs[ei[E + e]], 1);
        int code = ea[e * 3 + 0] + 6 * ea[e * 3 + 1] + 36 * ea[e * 3 + 2];
        epack[pos] = ei[e] | (code << 18);
    }
}

// ---------- shard reduce: out[t] = sum_s shard[s*C + t] ----------
__global__ __launch_bounds__(256) void k_red(const float* __restrict__ sh,
        float* __restrict__ out, int C) {
    int t = blockIdx.x * 256 + threadIdx.x;
    if (t >= C) return;
    float a = 0.f;
#pragma unroll
    for (int s = 0; s < NSHARD; ++s) a += sh[s * C + t];
    out[t] = a;
}

// ---------- zbuild: z = (1+eps)*hn + sum_e relu(hn_src + bsum[code]), hn = relu(bn_prev(y2h)) ----------
__global__ __launch_bounds__(256) void k_zbuild(const unsigned short* __restrict__ y2h,
        const int* __restrict__ rs, const int* __restrict__ epack,
        const float* __restrict__ btab, const float* __restrict__ sumprev,
        const float* __restrict__ gprev, const float* __restrict__ bprev,
        const float* __restrict__ epsv, int l, int mode, float invN,
        unsigned short* __restrict__ z, int N) {
    int gid = blockIdx.x * 256 + threadIdx.x;
    int n = gid >> 5;
    if (n >= N) return;
    int c = (gid & 31) << 2;
    float sc4[4] = {1.f, 1.f, 1.f, 1.f}, sh4[4] = {0.f, 0.f, 0.f, 0.f};
    if (mode) {
#pragma unroll
        for (int j = 0; j < 4; ++j) {
            float mu = sumprev[c + j] * invN;
            float var = sumprev[DD + c + j] * invN - mu * mu;
            float r = rsqrtf(var + 1e-5f);
            float sc = gprev[c + j] * r;
            sc4[j] = sc; sh4[j] = bprev[c + j] - mu * sc;
        }
    }
    int p0 = (n == 0) ? 0 : rs[n - 1];
    int p1 = rs[n];
    float ag[4] = {0.f, 0.f, 0.f, 0.f};
    for (int p = p0; p < p1; ++p) {
        int rec = epack[p];
        int src = rec & 0x3FFFF;
        int code = ((unsigned int)rec) >> 18;
        ushort4 hv = *(const ushort4*)(y2h + (size_t)src * DD + c);
        float4 bv = *(const float4*)(btab + (size_t)code * DD + c);
        float hs[4] = {bf2f(hv.x), bf2f(hv.y), bf2f(hv.z), bf2f(hv.w)};
        if (mode) {
#pragma unroll
            for (int j = 0; j < 4; ++j) hs[j] = fmaxf(hs[j] * sc4[j] + sh4[j], 0.f);
        }
        ag[0] += fmaxf(hs[0] + bv.x, 0.f);
        ag[1] += fmaxf(hs[1] + bv.y, 0.f);
        ag[2] += fmaxf(hs[2] + bv.z, 0.f);
        ag[3] += fmaxf(hs[3] + bv.w, 0.f);
    }
    float ep = 1.0f + epsv[l];
    ushort4 sv = *(const ushort4*)(y2h + (size_t)n * DD + c);
    float hz[4] = {bf2f(sv.x), bf2f(sv.y), bf2f(sv.z), bf2f(sv.w)};
    if (mode) {
#pragma unroll
        for (int j = 0; j < 4; ++j) hz[j] = fmaxf(hz[j] * sc4[j] + sh4[j], 0.f);
    }
    ushort4 o;
    o.x = f2bf(ep * hz[0] + ag[0]);
    o.y = f2bf(ep * hz[1] + ag[1]);
    o.z = f2bf(ep * hz[2] + ag[2]);
    o.w = f2bf(ep * hz[3] + ag[3]);
    *(ushort4*)(z + (size_t)n * DD + c) = o;
}

// ---------- GEMM1 (MFMA): y1 = z @ W1 + b1, sharded BN1 stats ----------
__global__ __launch_bounds__(256) void k_gemm1(const unsigned short* __restrict__ z,
        const unsigned short* __restrict__ W1l, const float* __restrict__ bias,
        unsigned short* __restrict__ y1, float* __restrict__ shard, int N) {
    __shared__ uv4 zt[64 * 16];    // 16KB
    __shared__ uv4 wt[256 * 4];    // 16KB
    int tid = threadIdx.x;
    int row0 = blockIdx.x * 64;
    int wave = tid >> 6, lane = tid & 63, lq = lane >> 4, lr = lane & 15;
    int rbase = tid >> 4, gz = tid & 15;

    // prefetch A tile (all loads in flight before use)
    uv4 zr[4];
#pragma unroll
    for (int i = 0; i < 4; ++i)
        zr[i] = *(const uv4*)(z + (size_t)(row0 + i * 16 + rbase) * DD + gz * 8);
    // prefetch W chunk 0
    const uv4* wsrc = (const uv4*)W1l;
    uv4 wr[4];
#pragma unroll
    for (int i = 0; i < 4; ++i) wr[i] = wsrc[i * 256 + tid];
#pragma unroll
    for (int i = 0; i < 4; ++i) {
        int row = i * 16 + rbase;
        zt[row * 16 + (gz ^ (row & 15))] = zr[i];
    }

    fv4 acc[4][4];
#pragma unroll
    for (int m = 0; m < 4; ++m)
#pragma unroll
        for (int nb = 0; nb < 4; ++nb) acc[m][nb] = (fv4){0.f, 0.f, 0.f, 0.f};

    for (int kc = 0; kc < 4; ++kc) {
        __syncthreads();
#pragma unroll
        for (int i = 0; i < 4; ++i) {
            int g = i * 256 + tid;
            int wn = g >> 2, gw = g & 3;
            wt[wn * 4 + (gw ^ ((wn >> 1) & 3))] = wr[i];
        }
        __syncthreads();
        if (kc < 3) {
#pragma unroll
            for (int i = 0; i < 4; ++i) wr[i] = wsrc[(size_t)(kc + 1) * 1024 + i * 256 + tid];
        }
        bfv8 a[4], b[4];
#pragma unroll
        for (int m = 0; m < 4; ++m) {
            int row = m * 16 + lr;
            a[m] = __builtin_bit_cast(bfv8, zt[row * 16 + ((kc * 4 + lq) ^ (row & 15))]);
        }
#pragma unroll
        for (int nb = 0; nb < 4; ++nb) {
            int col = wave * 64 + nb * 16 + lr;
            b[nb] = __builtin_bit_cast(bfv8, wt[col * 4 + (lq ^ ((col >> 1) & 3))]);
        }
#pragma unroll
        for (int m = 0; m < 4; ++m)
#pragma unroll
            for (int nb = 0; nb < 4; ++nb)
                acc[m][nb] = __builtin_amdgcn_mfma_f32_16x16x32_bf16(a[m], b[nb], acc[m][nb], 0, 0, 0);
    }

    float bv[4], s[4], q[4];
#pragma unroll
    for (int nb = 0; nb < 4; ++nb) {
        bv[nb] = bias[wave * 64 + nb * 16 + lr];
        s[nb] = 0.f; q[nb] = 0.f;
    }
#pragma unroll
    for (int m = 0; m < 4; ++m)
#pragma unroll
        for (int nb = 0; nb < 4; ++nb) {
            int col = wave * 64 + nb * 16 + lr;
#pragma unroll
            for (int r = 0; r < 4; ++r) {
                float v = acc[m][nb][r] + bv[nb];
                unsigned short ub = f2bf(v);
                float vr = bf2f(ub);
                int row = row0 + m * 16 + lq * 4 + r;
                y1[(size_t)row * HH + col] = ub;
                s[nb] += vr; q[nb] += vr * vr;
            }
        }
#pragma unroll
    for (int nb = 0; nb < 4; ++nb) {
        s[nb] += __shfl_xor(s[nb], 16); s[nb] += __shfl_xor(s[nb], 32);
        q[nb] += __shfl_xor(q[nb], 16); q[nb] += __shfl_xor(q[nb], 32);
    }
    if (lane < 16) {
        int shb = (blockIdx.x & (NSHARD - 1)) * 512;
#pragma unroll
        for (int nb = 0; nb < 4; ++nb) {
            int col = wave * 64 + nb * 16 + lr;
            atomicAdd(shard + shb + col, s[nb]);
            atomicAdd(shard + shb + 256 + col, q[nb]);
        }
    }
}

// ---------- GEMM2 (MFMA): y2h = bf16(relu(bn1(y1)) @ W2 + b2), sharded BN2 stats ----------
__global__ __launch_bounds__(256) void k_gemm2(const unsigned short* __restrict__ y1,
        const unsigned short* __restrict__ W2l, const float* __restrict__ bias,
        const float* __restrict__ sum1, const float* __restrict__ bn1g,
        const float* __restrict__ bn1b, float invN,
        unsigned short* __restrict__ y2h, float* __restrict__ shard, int N) {
    __shared__ uv4 at[64 * 32];    // 32KB
    __shared__ uv4 wt[128 * 4];    // 8KB
    int tid = threadIdx.x;
    int row0 = blockIdx.x * 64;
    int wave = tid >> 6, lane = tid & 63, lq = lane >> 4, lr = lane & 15;
    int rbase = tid >> 5, g = tid & 31;

    // prefetch full A tile (8 loads in flight) ...
    uv4 raw[8];
#pragma unroll
    for (int i = 0; i < 8; ++i)
        raw[i] = *((const uv4*)y1 + (size_t)(row0 + i * 8 + rbase) * 32 + g);
    // ... and W chunk 0
    const uv4* wbase = (const uv4*)W2l;
    uv4 wr[2];
    wr[0] = wbase[tid]; wr[1] = wbase[256 + tid];

    // per-thread BN1 scale/shift for its 8 channels (computed while loads fly)
    int g0 = g * 8;
    float scr[8], shr[8];
#pragma unroll
    for (int j = 0; j < 8; ++j) {
        float mu = sum1[g0 + j] * invN;
        float var = sum1[256 + g0 + j] * invN - mu * mu;
        float r = rsqrtf(var + 1e-5f);
        float sc = bn1g[g0 + j] * r;
        scr[j] = sc; shr[j] = bn1b[g0 + j] - mu * sc;
    }

#pragma unroll
    for (int i = 0; i < 8; ++i) {
        int row = i * 8 + rbase;
        uv4 p;
#pragma unroll
        for (int j = 0; j < 4; ++j) {
            float f0 = fmaxf(bf2f((unsigned short)(raw[i][j] & 0xFFFFu)) * scr[2 * j] + shr[2 * j], 0.f);
            float f1 = fmaxf(bf2f((unsigned short)(raw[i][j] >> 16)) * scr[2 * j + 1] + shr[2 * j + 1], 0.f);
            p[j] = (unsigned int)f2bf(f0) | ((unsigned int)f2bf(f1) << 16);
        }
        at[row * 32 + (g ^ (row & 15))] = p;
    }

    fv4 acc[4][2];
#pragma unroll
    for (int m = 0; m < 4; ++m) { acc[m][0] = (fv4){0.f,0.f,0.f,0.f}; acc[m][1] = (fv4){0.f,0.f,0.f,0.f}; }

    for (int kc = 0; kc < 8; ++kc) {
        __syncthreads();
        {
            int g2 = tid, wn = g2 >> 2, gw = g2 & 3;
            wt[wn * 4 + (gw ^ ((wn >> 1) & 3))] = wr[0];
            int g3 = 256 + tid, wn3 = g3 >> 2, gw3 = g3 & 3;
            wt[wn3 * 4 + (gw3 ^ ((wn3 >> 1) & 3))] = wr[1];
        }
        __syncthreads();
        if (kc < 7) {
            wr[0] = wbase[(size_t)(kc + 1) * 512 + tid];
            wr[1] = wbase[(size_t)(kc + 1) * 512 + 256 + tid];
        }
        bfv8 a[4], b[2];
#pragma unroll
        for (int m = 0; m < 4; ++m) {
            int row = m * 16 + lr;
            a[m] = __builtin_bit_cast(bfv8, at[row * 32 + ((kc * 4 + lq) ^ (row & 15))]);
        }
#pragma unroll
        for (int nb = 0; nb < 2; ++nb) {
            int col = wave * 32 + nb * 16 + lr;
            b[nb] = __builtin_bit_cast(bfv8, wt[col * 4 + (lq ^ ((col >> 1) & 3))]);
        }
#pragma unroll
        for (int m = 0; m < 4; ++m)
#pragma unroll
            for (int nb = 0; nb < 2; ++nb)
                acc[m][nb] = __builtin_amdgcn_mfma_f32_16x16x32_bf16(a[m], b[nb], acc[m][nb], 0, 0, 0);
    }

    float bv[2], s[2], q[2];
#pragma unroll
    for (int nb = 0; nb < 2; ++nb) {
        bv[nb] = bias[wave * 32 + nb * 16 + lr];
        s[nb] = 0.f; q[nb] = 0.f;
    }
#pragma unroll
    for (int m = 0; m < 4; ++m)
#pragma unroll
        for (int nb = 0; nb < 2; ++nb) {
            int col = wave * 32 + nb * 16 + lr;
#pragma unroll
            for (int r = 0; r < 4; ++r) {
                float v = acc[m][nb][r] + bv[nb];
                unsigned short ub = f2bf(v);
                float vr = bf2f(ub);
                int row = row0 + m * 16 + lq * 4 + r;
                y2h[(size_t)row * DD + col] = ub;
                s[nb] += vr; q[nb] += vr * vr;
            }
        }
#pragma unroll
    for (int nb = 0; nb < 2; ++nb) {
        s[nb] += __shfl_xor(s[nb], 16); s[nb] += __shfl_xor(s[nb], 32);
        q[nb] += __shfl_xor(q[nb], 16); q[nb] += __shfl_xor(q[nb], 32);
    }
    if (lane < 16) {
        int shb = (blockIdx.x & (NSHARD - 1)) * 256;
#pragma unroll
        for (int nb = 0; nb < 2; ++nb) {
            int col = wave * 32 + nb * 16 + lr;
            atomicAdd(shard + shb + col, s[nb]);
            atomicAdd(shard + shb + 128 + col, q[nb]);
        }
    }
}

// ---------- final: out = relu(bn2(y2h)) -> f32 ----------
__global__ __launch_bounds__(256) void k_bnfinal(const unsigned short* __restrict__ y2h,
        const float* __restrict__ sum2, const float* __restrict__ g,
        const float* __restrict__ b, float* __restrict__ out, float invN, int N) {
    __shared__ float scS[128], shS[128];
    int tid = threadIdx.x;
    if (tid < 128) {
        float mu = sum2[tid] * invN;
        float var = sum2[128 + tid] * invN - mu * mu;
        float r = rsqrtf(var + 1e-5f);
        float sc = g[tid] * r;
        scS[tid] = sc; shS[tid] = b[tid] - mu * sc;
    }
    __syncthreads();
    size_t base = ((size_t)blockIdx.x * 256 + tid) * 4;
    if (base >= (size_t)N * DD) return;
    int c = (int)(base & (DD - 1));
    ushort4 v = *(const ushort4*)(y2h + base);
    float4 o;
    o.x = fmaxf(bf2f(v.x) * scS[c] + shS[c], 0.f);
    o.y = fmaxf(bf2f(v.y) * scS[c + 1] + shS[c + 1], 0.f);
    o.z = fmaxf(bf2f(v.z) * scS[c + 2] + shS[c + 2], 0.f);
    o.w = fmaxf(bf2f(v.w) * scS[c + 3] + shS[c + 3], 0.f);
    *(float4*)(out + base) = o;
}

extern "C" void kernel_launch(void* const* d_in, const int* in_sizes, int n_in,
                              void* d_out, int out_size, void* d_ws, size_t ws_size,
                              hipStream_t stream) {
    const int* x = (const int*)d_in[0];
    const int* ei = (const int*)d_in[1];
    const int* ea = (const int*)d_in[2];
    const float* atom_emb = (const float*)d_in[3];
    const float* bond_emb = (const float*)d_in[4];
    const float* W1 = (const float*)d_in[5];
    const float* b1 = (const float*)d_in[6];
    const float* bn1_g = (const float*)d_in[7];
    const float* bn1_b = (const float*)d_in[8];
    const float* W2 = (const float*)d_in[9];
    const float* b2 = (const float*)d_in[10];
    const float* epsv = (const float*)d_in[11];
    const float* obn_g = (const float*)d_in[12];
    const float* obn_b = (const float*)d_in[13];
    int N = in_sizes[0] / NF_ATOM;   // 200000 (divisible by 64)
    int E = in_sizes[1] / 2;

    char* wsb = (char*)d_ws;
    unsigned short* y2h = (unsigned short*)wsb;                        // N*128 bf16 (state)
    unsigned short* zb = (unsigned short*)(wsb + (size_t)N * 256);     // N*128 bf16
    unsigned short* y1b = (unsigned short*)(wsb + (size_t)N * 512);    // N*256 bf16
    int* epack = (int*)(wsb + (size_t)N * 1024);                       // E int (packed)
    unsigned short* w1t = (unsigned short*)(wsb + (size_t)N * 1024 + (size_t)E * 4);
    unsigned short* w2t = w1t + 163840;
    int* rsarr = (int*)(w2t + 163840);                                 // N+1
    int* bsum = rsarr + (N + 1);                                       // 256
    int* boff = bsum + 256;                                            // 256
    float* st = (float*)(boff + 256);                                  // dense: 5*768 f32
    float* shard1 = st + NLAYER * 768;                                 // 32*512 f32
    float* shard2 = shard1 + NSHARD * 512;                             // 32*256 f32
    float* btab = shard2 + NSHARD * 256;                               // 5*216*128 f32
    float invN = 1.0f / (float)N;
    int nbk = (N + 1023) / 1024;

    k_wconv<<<1280, 256, 0, stream>>>(W1, W2, w1t, w2t);
    k_bsumtab<<<(NLAYER * NCODE * DD + 255) / 256, 256, 0, stream>>>(bond_emb, btab);
    hipMemsetAsync(rsarr, 0, ((size_t)N + 1) * 4, stream);
    k_deg<<<(E + 255) / 256, 256, 0, stream>>>(ei, rsarr, E);
    k_bsum<<<nbk, 256, 0, stream>>>(rsarr, bsum, N);
    k_bscan<<<1, 256, 0, stream>>>(bsum, boff, nbk);
    k_csr<<<nbk, 256, 0, stream>>>(rsarr, boff, rsarr, N, E);
    k_scatter<<<(E + 255) / 256, 256, 0, stream>>>(ei, ea, rsarr, epack, E);
    k_atom<<<(N * 32 + 255) / 256, 256, 0, stream>>>(x, atom_emb, y2h, N);

    int gb = N / 64;
    for (int l = 0; l < NLAYER; ++l) {
        float* sum1 = st + l * 768;
        float* sum2 = st + l * 768 + 512;
        const float* sumprev = (l == 0) ? st : (st + (l - 1) * 768 + 512);
        const float* gprev = (l == 0) ? obn_g : (obn_g + (l - 1) * DD);
        const float* bprev = (l == 0) ? obn_b : (obn_b + (l - 1) * DD);
        hipMemsetAsync(shard1, 0, (size_t)NSHARD * 768 * sizeof(float), stream);
        k_zbuild<<<(N * 32 + 255) / 256, 256, 0, stream>>>(y2h, rsarr, epack,
                btab + (size_t)l * NCODE * DD, sumprev, gprev, bprev,
                epsv, l, (l == 0) ? 0 : 1, invN, zb, N);
        k_gemm1<<<gb, 256, 0, stream>>>(zb, w1t + (size_t)l * 32768,
                b1 + l * HH, y1b, shard1, N);
        k_red<<<2, 256, 0, stream>>>(shard1, sum1, 512);
        k_gemm2<<<gb, 256, 0, stream>>>(y1b, w2t + (size_t)l * 32768, b2 + l * DD,
                sum1, bn1_g + l * HH, bn1_b + l * HH, invN, y2h, shard2, N);
        k_red<<<1, 256, 0, stream>>>(shard2, sum2, 256);
    }
    k_bnfinal<<<(int)(((size_t)N * DD / 4 + 255) / 256), 256, 0, stream>>>(
            y2h, st + 4 * 768 + 512, obn_g + 4 * DD, obn_b + 4 * DD, (float*)d_out, invN, N);
}

// Round 9
// 791.314 us; speedup vs baseline: 3.1488x; 1.0770x over previous
//
#include <hip/hip_runtime.h>

#define NF_ATOM 9
#define NF_BOND 3
#define DD 128
#define HH 256
#define NLAYER 5
#define NSHARD 32
#define NCODE 216

typedef float fv4 __attribute__((ext_vector_type(4)));
typedef __bf16 bfv8 __attribute__((ext_vector_type(8)));
typedef unsigned int uv4 __attribute__((ext_vector_type(4)));

__device__ inline unsigned short f2bf(float f) {
    unsigned int u = __builtin_bit_cast(unsigned int, f);
    u = u + 0x7FFFu + ((u >> 16) & 1u);
    return (unsigned short)(u >> 16);
}
__device__ inline float bf2f(unsigned short s) {
    unsigned int u = ((unsigned int)s) << 16;
    return __builtin_bit_cast(float, u);
}

// ---------- atom encoder: h0 -> bf16 state ----------
__global__ __launch_bounds__(256) void k_atom(const int* __restrict__ x,
        const float* __restrict__ emb, unsigned short* __restrict__ h, int N) {
    int gid = blockIdx.x * 256 + threadIdx.x;
    int n = gid >> 5;
    if (n >= N) return;
    int c = (gid & 31) << 2;
    const int* xr = x + n * NF_ATOM;
    float4 acc = make_float4(0.f, 0.f, 0.f, 0.f);
#pragma unroll
    for (int f = 0; f < NF_ATOM; ++f) {
        int idx = xr[f];
        float4 v = *(const float4*)(emb + ((size_t)(f * 120 + idx) * DD) + c);
        acc.x += v.x; acc.y += v.y; acc.z += v.z; acc.w += v.w;
    }
    ushort4 o;
    o.x = f2bf(acc.x); o.y = f2bf(acc.y); o.z = f2bf(acc.z); o.w = f2bf(acc.w);
    *(ushort4*)(h + (size_t)n * DD + c) = o;
}

// ---------- weight convert: f32 [K][N] -> bf16 chunk-major [l][kc][n][32k] ----------
__global__ __launch_bounds__(256) void k_wconv(const float* __restrict__ W1,
        const float* __restrict__ W2, unsigned short* __restrict__ W1t,
        unsigned short* __restrict__ W2t) {
    int id = blockIdx.x * 256 + threadIdx.x;
    const int T1 = NLAYER * 4 * 256 * 32;      // 163840
    if (id < T1) {
        int k = id & 31, n = (id >> 5) & 255, kc = (id >> 13) & 3, l = id >> 15;
        W1t[id] = f2bf(W1[((size_t)(l * 128 + kc * 32 + k)) * 256 + n]);
    } else {
        int id2 = id - T1;
        if (id2 >= NLAYER * 8 * 128 * 32) return;
        int k = id2 & 31, n = (id2 >> 5) & 127, kc = (id2 >> 12) & 7, l = id2 >> 15;
        W2t[id2] = f2bf(W2[((size_t)(l * 256 + kc * 32 + k)) * 128 + n]);
    }
}

// ---------- bond-sum table ----------
__global__ __launch_bounds__(256) void k_bsumtab(const float* __restrict__ bemb,
        float* __restrict__ tab) {
    int id = blockIdx.x * 256 + threadIdx.x;
    if (id >= NLAYER * NCODE * DD) return;
    int c = id & 127;
    int code = (id >> 7) % NCODE;
    int l = id / (NCODE * DD);
    int a0 = code % 6, a1 = (code / 6) % 6, a2 = code / 36;
    const float* bl = bemb + (size_t)l * NF_BOND * 6 * DD;
    tab[id] = bl[(0 * 6 + a0) * DD + c] + bl[(1 * 6 + a1) * DD + c] + bl[(2 * 6 + a2) * DD + c];
}

// ---------- CSR build ----------
__global__ __launch_bounds__(256) void k_deg(const int* __restrict__ ei, int* __restrict__ deg, int E) {
    int e = blockIdx.x * 256 + threadIdx.x;
    if (e < E) atomicAdd(&deg[ei[E + e]], 1);
}
__global__ __launch_bounds__(256) void k_bsum(const int* __restrict__ deg, int* __restrict__ bsum, int N) {
    __shared__ int red[256];
    int t = threadIdx.x, b = blockIdx.x;
    int i0 = b * 1024 + t * 4;
    int s = 0;
#pragma unroll
    for (int j = 0; j < 4; ++j) if (i0 + j < N) s += deg[i0 + j];
    red[t] = s; __syncthreads();
    for (int off = 128; off > 0; off >>= 1) {
        if (t < off) red[t] += red[t + off];
        __syncthreads();
    }
    if (t == 0) bsum[b] = red[0];
}
__global__ __launch_bounds__(256) void k_bscan(const int* __restrict__ bsum, int* __restrict__ boff, int nb) {
    __shared__ int ts[256];
    int t = threadIdx.x;
    int v = (t < nb) ? bsum[t] : 0;
    ts[t] = v; __syncthreads();
    for (int off = 1; off < 256; off <<= 1) {
        int u = (t >= off) ? ts[t - off] : 0;
        __syncthreads();
        ts[t] += u;
        __syncthreads();
    }
    if (t < nb) boff[t] = ts[t] - v;   // exclusive
}
__global__ __launch_bounds__(256) void k_csr(const int* deg, const int* __restrict__ boff,
        int* rs, int N, int E) {
    __shared__ int ts[256];
    int t = threadIdx.x, b = blockIdx.x;
    int i0 = b * 1024 + t * 4;
    int d[4];
#pragma unroll
    for (int j = 0; j < 4; ++j) d[j] = (i0 + j < N) ? deg[i0 + j] : 0;
    int tsum = d[0] + d[1] + d[2] + d[3];
    ts[t] = tsum; __syncthreads();
    for (int off = 1; off < 256; off <<= 1) {
        int u = (t >= off) ? ts[t - off] : 0;
        __syncthreads();
        ts[t] += u;
        __syncthreads();
    }
    int base = boff[b] + ts[t] - tsum;
    int p = 0;
#pragma unroll
    for (int j = 0; j < 4; ++j) {
        int dj = d[j];
        if (i0 + j < N) rs[i0 + j] = base + p;
        p += dj;
    }
    if (b == 0 && t == 0) rs[N] = E;
}
// packed record: src (18 bits) | code6 << 18
__global__ __launch_bounds__(256) void k_scatter(const int* __restrict__ ei,
        const int* __restrict__ ea, int* __restrict__ rs, int* __restrict__ epack, int E) {
    int e = blockIdx.x * 256 + threadIdx.x;
    if (e < E) {
        int pos = atomicAdd(&rs[ei[E + e]], 1);
        int code = ea[e * 3 + 0] + 6 * ea[e * 3 + 1] + 36 * ea[e * 3 + 2];
        epack[pos] = ei[e] | (code << 18);
    }
}

// ---------- shard reduce -> BN scale/shift tables ----------
// shard layout per s: [C sums][C sqsums], stride 2C. shift = bnb - mu*sc (+ gbias*sc if useb)
__global__ void k_red(const float* __restrict__ sh, int C, const float* __restrict__ bng,
        const float* __restrict__ bnb, const float* __restrict__ gbias, int useb,
        float invN, float* __restrict__ sc_out, float* __restrict__ sh_out) {
    int t = threadIdx.x;
    if (t >= C) return;
    float a = 0.f, qq = 0.f;
#pragma unroll
    for (int s = 0; s < NSHARD; ++s) {
        a += sh[s * 2 * C + t];
        qq += sh[s * 2 * C + C + t];
    }
    float mu = a * invN;
    float var = qq * invN - mu * mu;
    float r = rsqrtf(var + 1e-5f);
    float sc = bng[t] * r;
    float shift = bnb[t] - mu * sc;
    if (useb) shift += gbias[t] * sc;
    sc_out[t] = sc; sh_out[t] = shift;
}

// ---------- zbuild ----------
__device__ inline void edge_acc(ushort4 hv, float4 bv, float4 sc, float4 sh, int mode, float* ag) {
    float h0 = bf2f(hv.x), h1 = bf2f(hv.y), h2 = bf2f(hv.z), h3 = bf2f(hv.w);
    if (mode) {
        h0 = fmaxf(h0 * sc.x + sh.x, 0.f); h1 = fmaxf(h1 * sc.y + sh.y, 0.f);
        h2 = fmaxf(h2 * sc.z + sh.z, 0.f); h3 = fmaxf(h3 * sc.w + sh.w, 0.f);
    }
    ag[0] += fmaxf(h0 + bv.x, 0.f); ag[1] += fmaxf(h1 + bv.y, 0.f);
    ag[2] += fmaxf(h2 + bv.z, 0.f); ag[3] += fmaxf(h3 + bv.w, 0.f);
}

__global__ __launch_bounds__(256) void k_zbuild(const unsigned short* __restrict__ y2h,
        const int* __restrict__ rs, const int* __restrict__ epack,
        const float* __restrict__ btab, const float* __restrict__ sctab,
        const float* __restrict__ shtab, const float* __restrict__ epsv,
        int l, int mode, unsigned short* __restrict__ z, int N) {
    int gid = blockIdx.x * 256 + threadIdx.x;
    int n = gid >> 5;
    if (n >= N) return;
    int c = (gid & 31) << 2;
    float4 sc4 = make_float4(1.f, 1.f, 1.f, 1.f), sh4 = make_float4(0.f, 0.f, 0.f, 0.f);
    if (mode) { sc4 = *(const float4*)(sctab + c); sh4 = *(const float4*)(shtab + c); }
    int p0 = (n == 0) ? 0 : rs[n - 1];
    int p1 = rs[n];
    float ag[4] = {0.f, 0.f, 0.f, 0.f};
    int p = p0;
    for (; p + 2 <= p1; p += 2) {
        int rec0 = epack[p], rec1 = epack[p + 1];
        int s0 = rec0 & 0x3FFFF, s1 = rec1 & 0x3FFFF;
        int c0 = ((unsigned int)rec0) >> 18, c1 = ((unsigned int)rec1) >> 18;
        ushort4 h0 = *(const ushort4*)(y2h + (size_t)s0 * DD + c);
        ushort4 h1 = *(const ushort4*)(y2h + (size_t)s1 * DD + c);
        float4 b0 = *(const float4*)(btab + (size_t)c0 * DD + c);
        float4 b1 = *(const float4*)(btab + (size_t)c1 * DD + c);
        edge_acc(h0, b0, sc4, sh4, mode, ag);
        edge_acc(h1, b1, sc4, sh4, mode, ag);
    }
    if (p < p1) {
        int rec = epack[p];
        int s0 = rec & 0x3FFFF;
        int c0 = ((unsigned int)rec) >> 18;
        ushort4 h0 = *(const ushort4*)(y2h + (size_t)s0 * DD + c);
        float4 b0 = *(const float4*)(btab + (size_t)c0 * DD + c);
        edge_acc(h0, b0, sc4, sh4, mode, ag);
    }
    float ep = 1.0f + epsv[l];
    ushort4 sv = *(const ushort4*)(y2h + (size_t)n * DD + c);
    float hz[4] = {bf2f(sv.x), bf2f(sv.y), bf2f(sv.z), bf2f(sv.w)};
    if (mode) {
        hz[0] = fmaxf(hz[0] * sc4.x + sh4.x, 0.f);
        hz[1] = fmaxf(hz[1] * sc4.y + sh4.y, 0.f);
        hz[2] = fmaxf(hz[2] * sc4.z + sh4.z, 0.f);
        hz[3] = fmaxf(hz[3] * sc4.w + sh4.w, 0.f);
    }
    ushort4 o;
    o.x = f2bf(ep * hz[0] + ag[0]);
    o.y = f2bf(ep * hz[1] + ag[1]);
    o.z = f2bf(ep * hz[2] + ag[2]);
    o.w = f2bf(ep * hz[3] + ag[3]);
    *(ushort4*)(z + (size_t)n * DD + c) = o;
}

// ---------- stats pass: BN1 sum/sumsq of (z @ W1 + b1), no y1 write ----------
__global__ __launch_bounds__(256) void k_stat1(const unsigned short* __restrict__ z,
        const unsigned short* __restrict__ W1l, const float* __restrict__ bias,
        float* __restrict__ shard, int N) {
    __shared__ uv4 zt[64 * 16];    // 16KB
    __shared__ uv4 wt[256 * 4];    // 16KB
    int tid = threadIdx.x;
    int row0 = blockIdx.x * 64;
    int wave = tid >> 6, lane = tid & 63, lq = lane >> 4, lr = lane & 15;
    int rbase = tid >> 4, gz = tid & 15;

    uv4 zr[4];
#pragma unroll
    for (int i = 0; i < 4; ++i)
        zr[i] = *(const uv4*)(z + (size_t)(row0 + i * 16 + rbase) * DD + gz * 8);
    const uv4* wsrc = (const uv4*)W1l;
    uv4 wr[4];
#pragma unroll
    for (int i = 0; i < 4; ++i) wr[i] = wsrc[i * 256 + tid];
#pragma unroll
    for (int i = 0; i < 4; ++i) {
        int row = i * 16 + rbase;
        zt[row * 16 + (gz ^ (row & 15))] = zr[i];
    }

    fv4 acc[4][4];
#pragma unroll
    for (int m = 0; m < 4; ++m)
#pragma unroll
        for (int nb = 0; nb < 4; ++nb) acc[m][nb] = (fv4){0.f, 0.f, 0.f, 0.f};

    for (int kc = 0; kc < 4; ++kc) {
        __syncthreads();
#pragma unroll
        for (int i = 0; i < 4; ++i) {
            int g = i * 256 + tid;
            int wn = g >> 2, gw = g & 3;
            wt[wn * 4 + (gw ^ ((wn >> 1) & 3))] = wr[i];
        }
        __syncthreads();
        if (kc < 3) {
#pragma unroll
            for (int i = 0; i < 4; ++i) wr[i] = wsrc[(size_t)(kc + 1) * 1024 + i * 256 + tid];
        }
        bfv8 a[4], b[4];
#pragma unroll
        for (int m = 0; m < 4; ++m) {
            int row = m * 16 + lr;
            a[m] = __builtin_bit_cast(bfv8, zt[row * 16 + ((kc * 4 + lq) ^ (row & 15))]);
        }
#pragma unroll
        for (int nb = 0; nb < 4; ++nb) {
            int col = wave * 64 + nb * 16 + lr;
            b[nb] = __builtin_bit_cast(bfv8, wt[col * 4 + (lq ^ ((col >> 1) & 3))]);
        }
#pragma unroll
        for (int m = 0; m < 4; ++m)
#pragma unroll
            for (int nb = 0; nb < 4; ++nb)
                acc[m][nb] = __builtin_amdgcn_mfma_f32_16x16x32_bf16(a[m], b[nb], acc[m][nb], 0, 0, 0);
    }

    float bv[4], s[4], q[4];
#pragma unroll
    for (int nb = 0; nb < 4; ++nb) {
        bv[nb] = bias[wave * 64 + nb * 16 + lr];
        s[nb] = 0.f; q[nb] = 0.f;
    }
#pragma unroll
    for (int m = 0; m < 4; ++m)
#pragma unroll
        for (int nb = 0; nb < 4; ++nb)
#pragma unroll
            for (int r = 0; r < 4; ++r) {
                float v = acc[m][nb][r] + bv[nb];
                s[nb] += v; q[nb] += v * v;
            }
#pragma unroll
    for (int nb = 0; nb < 4; ++nb) {
        s[nb] += __shfl_xor(s[nb], 16); s[nb] += __shfl_xor(s[nb], 32);
        q[nb] += __shfl_xor(q[nb], 16); q[nb] += __shfl_xor(q[nb], 32);
    }
    if (lane < 16) {
        int shb = (blockIdx.x & (NSHARD - 1)) * 512;
#pragma unroll
        for (int nb = 0; nb < 4; ++nb) {
            int col = wave * 64 + nb * 16 + lr;
            atomicAdd(shard + shb + col, s[nb]);
            atomicAdd(shard + shb + 256 + col, q[nb]);
        }
    }
}

// ---------- fused: y2h = bf16( relu(bn1(z@W1+b1)) @ W2 + b2 ), BN2 stat shards ----------
__global__ __launch_bounds__(256) void k_fgemm(const unsigned short* __restrict__ z,
        const unsigned short* __restrict__ W1l, const unsigned short* __restrict__ W2l,
        const float* __restrict__ sc1, const float* __restrict__ sh1,
        const float* __restrict__ bias2,
        unsigned short* __restrict__ y2h, float* __restrict__ shard, int N) {
    __shared__ uv4 smem[2560];           // 40KB union
    uv4* zt = smem;                      // phase1: [64*16] 16KB
    uv4* wt = smem + 1024;               // phase1: [256*4] 16KB
    uv4* at = smem;                      // phase2: [64*32] 32KB (aliases zt+wt)
    uv4* wt2 = smem + 2048;              // phase2: [128*4] 8KB
    int tid = threadIdx.x;
    int row0 = blockIdx.x * 64;
    int wave = tid >> 6, lane = tid & 63, lq = lane >> 4, lr = lane & 15;
    int rbase = tid >> 4, gz = tid & 15;

    // prefetch z tile + W1 chunk0
    uv4 zr[4];
#pragma unroll
    for (int i = 0; i < 4; ++i)
        zr[i] = *(const uv4*)(z + (size_t)(row0 + i * 16 + rbase) * DD + gz * 8);
    const uv4* w1src = (const uv4*)W1l;
    uv4 wr[4];
#pragma unroll
    for (int i = 0; i < 4; ++i) wr[i] = w1src[i * 256 + tid];
#pragma unroll
    for (int i = 0; i < 4; ++i) {
        int row = i * 16 + rbase;
        zt[row * 16 + (gz ^ (row & 15))] = zr[i];
    }

    // phase 1: acc1[mc][nr] = W1^T-tile x z-tile  (D rows = y1 cols, D cols = z rows)
    fv4 acc1[4][4];
#pragma unroll
    for (int mc = 0; mc < 4; ++mc)
#pragma unroll
        for (int nr = 0; nr < 4; ++nr) acc1[mc][nr] = (fv4){0.f, 0.f, 0.f, 0.f};

    for (int kc = 0; kc < 4; ++kc) {
        __syncthreads();
#pragma unroll
        for (int i = 0; i < 4; ++i) {
            int g = i * 256 + tid;
            int wn = g >> 2, gw = g & 3;
            wt[wn * 4 + (gw ^ ((wn >> 1) & 3))] = wr[i];
        }
        __syncthreads();
        if (kc < 3) {
#pragma unroll
            for (int i = 0; i < 4; ++i) wr[i] = w1src[(size_t)(kc + 1) * 1024 + i * 256 + tid];
        }
        bfv8 wf[4], zf[4];
#pragma unroll
        for (int mc = 0; mc < 4; ++mc) {
            int col = wave * 64 + mc * 16 + lr;
            wf[mc] = __builtin_bit_cast(bfv8, wt[col * 4 + (lq ^ ((col >> 1) & 3))]);
        }
#pragma unroll
        for (int nr = 0; nr < 4; ++nr) {
            int row = nr * 16 + lr;
            zf[nr] = __builtin_bit_cast(bfv8, zt[row * 16 + ((kc * 4 + lq) ^ (row & 15))]);
        }
#pragma unroll
        for (int mc = 0; mc < 4; ++mc)
#pragma unroll
            for (int nr = 0; nr < 4; ++nr)
                acc1[mc][nr] = __builtin_amdgcn_mfma_f32_16x16x32_bf16(wf[mc], zf[nr], acc1[mc][nr], 0, 0, 0);
    }
    __syncthreads();   // all LDS reads of zt/wt complete before at-writes

    // prefetch W2 chunk0 (latency hides under epilogue1)
    const uv4* w2src = (const uv4*)W2l;
    uv4 wr2[2];
    wr2[0] = w2src[tid]; wr2[1] = w2src[256 + tid];

    // epilogue1: bn1-apply + relu + bf16 pack -> at tile (y1n, [64 rows][256 cols])
#pragma unroll
    for (int mc = 0; mc < 4; ++mc) {
        int ycol0 = wave * 64 + mc * 16 + lq * 4;
        float4 s4 = *(const float4*)(sc1 + ycol0);
        float4 h4 = *(const float4*)(sh1 + ycol0);
        int gg = wave * 8 + mc * 2 + (lq >> 1);
#pragma unroll
        for (int nr = 0; nr < 4; ++nr) {
            int zrow = nr * 16 + lr;
            float v0 = fmaxf(acc1[mc][nr][0] * s4.x + h4.x, 0.f);
            float v1 = fmaxf(acc1[mc][nr][1] * s4.y + h4.y, 0.f);
            float v2 = fmaxf(acc1[mc][nr][2] * s4.z + h4.z, 0.f);
            float v3 = fmaxf(acc1[mc][nr][3] * s4.w + h4.w, 0.f);
            uint2 pk;
            pk.x = (unsigned int)f2bf(v0) | ((unsigned int)f2bf(v1) << 16);
            pk.y = (unsigned int)f2bf(v2) | ((unsigned int)f2bf(v3) << 16);
            int gs = gg ^ (zrow & 15);
            ((uint2*)at)[(zrow * 32 + gs) * 2 + (lq & 1)] = pk;
        }
    }

    // phase 2: y2 = at @ W2
    fv4 acc2[4][2];
#pragma unroll
    for (int m = 0; m < 4; ++m) { acc2[m][0] = (fv4){0.f,0.f,0.f,0.f}; acc2[m][1] = (fv4){0.f,0.f,0.f,0.f}; }

    for (int kc = 0; kc < 8; ++kc) {
        __syncthreads();
        {
            int wn = tid >> 2, gw = tid & 3;
            wt2[wn * 4 + (gw ^ ((wn >> 1) & 3))] = wr2[0];
            int g3 = 256 + tid, wn3 = g3 >> 2, gw3 = g3 & 3;
            wt2[wn3 * 4 + (gw3 ^ ((wn3 >> 1) & 3))] = wr2[1];
        }
        __syncthreads();
        if (kc < 7) {
            wr2[0] = w2src[(size_t)(kc + 1) * 512 + tid];
            wr2[1] = w2src[(size_t)(kc + 1) * 512 + 256 + tid];
        }
        bfv8 a[4], b[2];
#pragma unroll
        for (int m = 0; m < 4; ++m) {
            int row = m * 16 + lr;
            a[m] = __builtin_bit_cast(bfv8, at[row * 32 + ((kc * 4 + lq) ^ (row & 15))]);
        }
#pragma unroll
        for (int nb = 0; nb < 2; ++nb) {
            int col = wave * 32 + nb * 16 + lr;
            b[nb] = __builtin_bit_cast(bfv8, wt2[col * 4 + (lq ^ ((col >> 1) & 3))]);
        }
#pragma unroll
        for (int m = 0; m < 4; ++m)
#pragma unroll
            for (int nb = 0; nb < 2; ++nb)
                acc2[m][nb] = __builtin_amdgcn_mfma_f32_16x16x32_bf16(a[m], b[nb], acc2[m][nb], 0, 0, 0);
    }

    float bv[2], s[2], q[2];
#pragma unroll
    for (int nb = 0; nb < 2; ++nb) {
        bv[nb] = bias2[wave * 32 + nb * 16 + lr];
        s[nb] = 0.f; q[nb] = 0.f;
    }
#pragma unroll
    for (int m = 0; m < 4; ++m)
#pragma unroll
        for (int nb = 0; nb < 2; ++nb) {
            int col = wave * 32 + nb * 16 + lr;
#pragma unroll
            for (int r = 0; r < 4; ++r) {
                float v = acc2[m][nb][r] + bv[nb];
                unsigned short ub = f2bf(v);
                float vr = bf2f(ub);
                int row = row0 + m * 16 + lq * 4 + r;
                y2h[(size_t)row * DD + col] = ub;
                s[nb] += vr; q[nb] += vr * vr;
            }
        }
#pragma unroll
    for (int nb = 0; nb < 2; ++nb) {
        s[nb] += __shfl_xor(s[nb], 16); s[nb] += __shfl_xor(s[nb], 32);
        q[nb] += __shfl_xor(q[nb], 16); q[nb] += __shfl_xor(q[nb], 32);
    }
    if (lane < 16) {
        int shb = (blockIdx.x & (NSHARD - 1)) * 256;
#pragma unroll
        for (int nb = 0; nb < 2; ++nb) {
            int col = wave * 32 + nb * 16 + lr;
            atomicAdd(shard + shb + col, s[nb]);
            atomicAdd(shard + shb + 128 + col, q[nb]);
        }
    }
}

// ---------- final: out = relu(bn2(y2h)) -> f32 ----------
__global__ __launch_bounds__(256) void k_bnfinal(const unsigned short* __restrict__ y2h,
        const float* __restrict__ sc2, const float* __restrict__ sh2,
        float* __restrict__ out, int N) {
    size_t base = ((size_t)blockIdx.x * 256 + threadIdx.x) * 4;
    if (base >= (size_t)N * DD) return;
    int c = (int)(base & (DD - 1));
    ushort4 v = *(const ushort4*)(y2h + base);
    float4 s = *(const float4*)(sc2 + c);
    float4 t = *(const float4*)(sh2 + c);
    float4 o;
    o.x = fmaxf(bf2f(v.x) * s.x + t.x, 0.f);
    o.y = fmaxf(bf2f(v.y) * s.y + t.y, 0.f);
    o.z = fmaxf(bf2f(v.z) * s.z + t.z, 0.f);
    o.w = fmaxf(bf2f(v.w) * s.w + t.w, 0.f);
    *(float4*)(out + base) = o;
}

extern "C" void kernel_launch(void* const* d_in, const int* in_sizes, int n_in,
                              void* d_out, int out_size, void* d_ws, size_t ws_size,
                              hipStream_t stream) {
    const int* x = (const int*)d_in[0];
    const int* ei = (const int*)d_in[1];
    const int* ea = (const int*)d_in[2];
    const float* atom_emb = (const float*)d_in[3];
    const float* bond_emb = (const float*)d_in[4];
    const float* W1 = (const float*)d_in[5];
    const float* b1 = (const float*)d_in[6];
    const float* bn1_g = (const float*)d_in[7];
    const float* bn1_b = (const float*)d_in[8];
    const float* W2 = (const float*)d_in[9];
    const float* b2 = (const float*)d_in[10];
    const float* epsv = (const float*)d_in[11];
    const float* obn_g = (const float*)d_in[12];
    const float* obn_b = (const float*)d_in[13];
    int N = in_sizes[0] / NF_ATOM;   // 200000 (divisible by 64)
    int E = in_sizes[1] / 2;

    char* wsb = (char*)d_ws;
    unsigned short* y2h = (unsigned short*)wsb;                        // N*128 bf16 (state)
    unsigned short* zb = (unsigned short*)(wsb + (size_t)N * 256);     // N*128 bf16
    int* epack = (int*)(wsb + (size_t)N * 512);                        // E int
    unsigned short* w1t = (unsigned short*)(wsb + (size_t)N * 512 + (size_t)E * 4);
    unsigned short* w2t = w1t + 163840;
    float* btab = (float*)((char*)w2t + 327680);                       // 5*216*128 f32
    float* sc1 = btab + NLAYER * NCODE * DD;                           // 256
    float* sh1 = sc1 + 256;                                            // 256
    float* sc2 = sh1 + 256;                                            // 128
    float* sh2 = sc2 + 128;                                            // 128
    float* shard1 = sh2 + 128;                                         // 32*512
    float* shard2 = shard1 + NSHARD * 512;                             // 32*256
    int* rsarr = (int*)(shard2 + NSHARD * 256);                        // N+1
    int* bsum = rsarr + (N + 1);                                       // 256
    int* boff = bsum + 256;                                            // 256
    float invN = 1.0f / (float)N;
    int nbk = (N + 1023) / 1024;

    k_wconv<<<1280, 256, 0, stream>>>(W1, W2, w1t, w2t);
    k_bsumtab<<<(NLAYER * NCODE * DD + 255) / 256, 256, 0, stream>>>(bond_emb, btab);
    hipMemsetAsync(rsarr, 0, ((size_t)N + 1) * 4, stream);
    k_deg<<<(E + 255) / 256, 256, 0, stream>>>(ei, rsarr, E);
    k_bsum<<<nbk, 256, 0, stream>>>(rsarr, bsum, N);
    k_bscan<<<1, 256, 0, stream>>>(bsum, boff, nbk);
    k_csr<<<nbk, 256, 0, stream>>>(rsarr, boff, rsarr, N, E);
    k_scatter<<<(E + 255) / 256, 256, 0, stream>>>(ei, ea, rsarr, epack, E);
    k_atom<<<(N * 32 + 255) / 256, 256, 0, stream>>>(x, atom_emb, y2h, N);

    int gb = N / 64;
    for (int l = 0; l < NLAYER; ++l) {
        hipMemsetAsync(shard1, 0, (size_t)NSHARD * 768 * sizeof(float), stream);
        k_zbuild<<<(N * 32 + 255) / 256, 256, 0, stream>>>(y2h, rsarr, epack,
                btab + (size_t)l * NCODE * DD, sc2, sh2, epsv, l, (l == 0) ? 0 : 1, zb, N);
        k_stat1<<<gb, 256, 0, stream>>>(zb, w1t + (size_t)l * 32768, b1 + l * HH, shard1, N);
        k_red<<<1, 256, 0, stream>>>(shard1, 256, bn1_g + l * HH, bn1_b + l * HH,
                b1 + l * HH, 1, invN, sc1, sh1);
        k_fgemm<<<gb, 256, 0, stream>>>(zb, w1t + (size_t)l * 32768, w2t + (size_t)l * 32768,
                sc1, sh1, b2 + l * DD, y2h, shard2, N);
        k_red<<<1, 128, 0, stream>>>(shard2, 128, obn_g + l * DD, obn_b + l * DD,
                (const float*)nullptr, 0, invN, sc2, sh2);
    }
    k_bnfinal<<<(int)(((size_t)N * DD / 4 + 255) / 256), 256, 0, stream>>>(
            y2h, sc2, sh2, (float*)d_out, N);
}